// Round 2
// baseline (3482.605 us; speedup 1.0000x reference)
//
#include <hip/hip_runtime.h>
#include <cstddef>

// ---------------- problem dims ----------------
constexpr int BB   = 4;
constexpr int LX   = 126975;
constexpr int H0   = 4096, W0 = 61;          // c_in spatial
constexpr int C1   = 128, H1 = 1025, W1 = 16;
constexpr int C2   = 256, H2 = 513,  W2 = 8;
constexpr int C3   = 128;
constexpr int NN   = H2 * W2;                // 4104
constexpr int NPAD = 4224;                   // 33*128
constexpr int JSPAN = 520;                   // 8 splits cover 4104

// ---------------- workspace layout (float offsets), lifetime-overlapped ----
// Region A [0, 8,396,800): h1 (conv1->conv2); then p3 (conv3->c5) at 0 and
//   flash partials accp/ml after c5 (disjoint offsets from p3 anyway).
// Region B [8,396,800, +4,202,496): p2 (conv2->conv3); then f1,f2,q,k,v,sa,sc.
// Total = 12,603,392 floats = 50.4 MB.
constexpr size_t SZ_H1    = (size_t)BB * C1 * H1 * W1;    // 8,396,800
constexpr size_t SZ_P2    = (size_t)BB * C2 * NN;         // 4,202,496
constexpr size_t SZ_P3    = (size_t)BB * C3 * NN;         // 2,101,248
constexpr size_t SZ_F     = (size_t)BB * 32 * NN;         //   525,312
constexpr size_t SZ_QK    = (size_t)BB * 4 * NN;          //    65,664
constexpr size_t SZ_ACCP  = (size_t)8 * BB * 32 * NPAD;   // 4,325,376
constexpr size_t SZ_ML    = (size_t)8 * BB * 2 * NPAD;    //   270,336

constexpr size_t OFF_H1   = 0;
constexpr size_t OFF_P3   = 0;                  // reuses h1 (dead after conv2)
constexpr size_t OFF_ACCP = SZ_P3;              // 2,101,248
constexpr size_t OFF_ML   = OFF_ACCP + SZ_ACCP; // ends 6,696,960 < 8,396,800
constexpr size_t RB       = SZ_H1;              // 8,396,800
constexpr size_t OFF_P2   = RB;
constexpr size_t OFF_F1   = RB;                 // reuses p2 (dead after conv3)
constexpr size_t OFF_F2   = OFF_F1 + SZ_F;
constexpr size_t OFF_Q    = OFF_F2 + SZ_F;
constexpr size_t OFF_K    = OFF_Q  + SZ_QK;
constexpr size_t OFF_V    = OFF_K  + SZ_QK;
constexpr size_t OFF_SA   = OFF_V  + SZ_F;
constexpr size_t OFF_SC   = OFF_SA + SZ_F;      // ends RB+2,757,888 < RB+4,202,496
constexpr size_t OFF_EN   = RB + SZ_P2;         // 4096 floats
constexpr size_t WS_FLOATS = OFF_EN + 4096;     // 12,603,392 (~50.4 MB)

__device__ __forceinline__ float frelu(float x) { return x > 0.f ? x : 0.f; }

// ================= conv1: 8x8 s4 p4, cin=1, 128 oc, +bias+relu ================
// grid (65, 16, 4), block 256.  Input gather (unfold+reshape) fused into staging.
__global__ __launch_bounds__(256) void k_conv1(const float* __restrict__ x,
                                               const float* __restrict__ w1,
                                               const float* __restrict__ b1,
                                               float* __restrict__ h1) {
  __shared__ __align__(16) float tile[68 * 68];
  const int oh0 = blockIdx.x * 16;
  const int oc0 = blockIdx.y * 8;
  const int b   = blockIdx.z;
  const int tid = threadIdx.x;
  const int ih0 = oh0 * 4 - 4;
  for (int e = tid; e < 68 * 68; e += 256) {
    int row = e / 68, col = e - row * 68;
    int ih = ih0 + row, iw = col - 4;
    float v = 0.f;
    if (ih >= 0 && ih < H0 && iw >= 0 && iw < W0) {
      int l   = ih * W0 + iw;
      int pos = (l >> 12) * 2048 + (l & 4095);
      if (pos < LX) v = x[(size_t)b * LX + pos];
    }
    tile[e] = v;
  }
  __syncthreads();
  const int oh_l = tid >> 4, ow = tid & 15;
  float acc[8];
#pragma unroll
  for (int o = 0; o < 8; ++o) acc[o] = 0.f;
#pragma unroll
  for (int kh = 0; kh < 8; ++kh) {
    const float* rp = &tile[(4 * oh_l + kh) * 68 + 4 * ow];
    float4 a0 = *(const float4*)rp;
    float4 a1 = *(const float4*)(rp + 4);
    float r[8] = {a0.x, a0.y, a0.z, a0.w, a1.x, a1.y, a1.z, a1.w};
#pragma unroll
    for (int kw = 0; kw < 8; ++kw) {
#pragma unroll
      for (int o = 0; o < 8; ++o)
        acc[o] = fmaf(r[kw], w1[(oc0 + o) * 64 + kh * 8 + kw], acc[o]);
    }
  }
  const int oh = oh0 + oh_l;
  if (oh < H1) {
#pragma unroll
    for (int o = 0; o < 8; ++o) {
      float v = frelu(acc[o] + b1[oc0 + o]);
      h1[(((size_t)b * C1 + oc0 + o) * H1 + oh) * W1 + ow] = v;
    }
  }
}

// ================= conv2: 5x5 s2 p2, full cin 128, +bias+relu ================
// grid (33, 4, 4).  block 128: thread = 8oc x 8ow, 16 oh rows.
__global__ __launch_bounds__(128) void k_conv2(const float* __restrict__ h1,
                                               const float* __restrict__ w2,
                                               const float* __restrict__ b2,
                                               float* __restrict__ p2) {
  constexpr int S = 20;
  __shared__ __align__(16) float tin[4 * 35 * S];   // 2800
  __shared__ __align__(16) float twt[100 * 64];     // 6400
  const int oh0  = blockIdx.x * 16;
  const int oc0  = blockIdx.y * 64;
  const int b    = blockIdx.z;
  const int tid  = threadIdx.x;
  const int oh_l = tid & 15, ocg = tid >> 4;
  float acc[8][8] = {};
  for (int cc = 0; cc < 32; ++cc) {
    __syncthreads();
    for (int e = tid; e < 4 * 35 * 16; e += 128) {
      int ci = e / 560, r = e - ci * 560;
      int tr = r >> 4, c = r & 15;
      int ih = oh0 * 2 - 2 + tr;
      int cin = cc * 4 + ci;
      float v = 0.f;
      if (ih >= 0 && ih < H1) v = h1[(((size_t)b * C1 + cin) * H1 + ih) * W1 + c];
      tin[(ci * 35 + tr) * S + c] = v;
    }
    for (int e = tid; e < 6400; e += 128) {
      int oc_l = e & 63, t = e >> 6;
      twt[t * 64 + oc_l] = w2[(size_t)(oc0 + oc_l) * 3200 + cc * 100 + t];
    }
    __syncthreads();
#pragma unroll 1
    for (int ci = 0; ci < 4; ++ci) {
#pragma unroll
      for (int kh = 0; kh < 5; ++kh) {
        const float* rp = &tin[(ci * 35 + 2 * oh_l + kh) * S];
        float4 a0 = *(const float4*)rp;
        float4 a1 = *(const float4*)(rp + 4);
        float4 a2 = *(const float4*)(rp + 8);
        float4 a3 = *(const float4*)(rp + 12);
        float rr[19];
        rr[0] = 0.f; rr[1] = 0.f; rr[18] = 0.f;
        rr[2] = a0.x; rr[3] = a0.y; rr[4] = a0.z; rr[5] = a0.w;
        rr[6] = a1.x; rr[7] = a1.y; rr[8] = a1.z; rr[9] = a1.w;
        rr[10] = a2.x; rr[11] = a2.y; rr[12] = a2.z; rr[13] = a2.w;
        rr[14] = a3.x; rr[15] = a3.y; rr[16] = a3.z; rr[17] = a3.w;
#pragma unroll
        for (int kw = 0; kw < 5; ++kw) {
          const float* wp = &twt[(ci * 25 + kh * 5 + kw) * 64 + ocg * 8];
          float4 w0 = *(const float4*)wp;
          float4 w1v = *(const float4*)(wp + 4);
          float wv[8] = {w0.x, w0.y, w0.z, w0.w, w1v.x, w1v.y, w1v.z, w1v.w};
#pragma unroll
          for (int o = 0; o < 8; ++o)
#pragma unroll
            for (int ow = 0; ow < 8; ++ow)
              acc[o][ow] = fmaf(rr[2 * ow + kw], wv[o], acc[o][ow]);
        }
      }
    }
  }
  const int oh = oh0 + oh_l;
  if (oh < H2) {
#pragma unroll
    for (int o = 0; o < 8; ++o) {
      int oc = oc0 + ocg * 8 + o;
      float bo = b2[oc];
      float* dst = &p2[((size_t)b * C2 + oc) * NN + oh * 8];
      *(float4*)dst       = make_float4(frelu(acc[o][0] + bo), frelu(acc[o][1] + bo),
                                        frelu(acc[o][2] + bo), frelu(acc[o][3] + bo));
      *(float4*)(dst + 4) = make_float4(frelu(acc[o][4] + bo), frelu(acc[o][5] + bo),
                                        frelu(acc[o][6] + bo), frelu(acc[o][7] + bo));
    }
  }
}

// ================= conv3: 3x3 s1 p1, full cin 256, +bias+relu ================
// grid (33, 4, 4): y = 32-oc chunk.  block 128: 16 oh x (8 grp x 4 oc).
__global__ __launch_bounds__(128) void k_conv3(const float* __restrict__ p2,
                                               const float* __restrict__ w3,
                                               const float* __restrict__ b3,
                                               float* __restrict__ p3) {
  __shared__ __align__(16) float tin[8 * 18 * 12];  // 1728
  __shared__ __align__(16) float twt[72 * 32];      // 2304
  const int oh0 = blockIdx.x * 16;
  const int oc0 = blockIdx.y * 32;
  const int b   = blockIdx.z;
  const int tid = threadIdx.x;
  const int oh_l = tid & 15, ocg = tid >> 4;
  float acc[4][8] = {};
  for (int cc = 0; cc < 32; ++cc) {
    __syncthreads();
    for (int e = tid; e < 1152; e += 128) {
      int ci = e / 144, r = e - ci * 144;
      int tr = r >> 3, c = r & 7;
      int ih = oh0 - 1 + tr;
      int cin = cc * 8 + ci;
      float v = 0.f;
      if (ih >= 0 && ih < H2) v = p2[((size_t)b * C2 + cin) * NN + ih * 8 + c];
      tin[(ci * 18 + tr) * 12 + c] = v;
    }
    for (int e = tid; e < 2304; e += 128) {
      int oc_l = e & 31, t = e >> 5;
      twt[t * 32 + oc_l] = w3[(size_t)(oc0 + oc_l) * 2304 + cc * 72 + t];
    }
    __syncthreads();
#pragma unroll 1
    for (int ci = 0; ci < 8; ++ci) {
#pragma unroll
      for (int kh = 0; kh < 3; ++kh) {
        const float* rp = &tin[(ci * 18 + oh_l + kh) * 12];
        float4 a0 = *(const float4*)rp;
        float4 a1 = *(const float4*)(rp + 4);
        float rr[10];
        rr[0] = 0.f; rr[9] = 0.f;
        rr[1] = a0.x; rr[2] = a0.y; rr[3] = a0.z; rr[4] = a0.w;
        rr[5] = a1.x; rr[6] = a1.y; rr[7] = a1.z; rr[8] = a1.w;
#pragma unroll
        for (int kw = 0; kw < 3; ++kw) {
          float4 wv = *(const float4*)&twt[(ci * 9 + kh * 3 + kw) * 32 + ocg * 4];
#pragma unroll
          for (int ow = 0; ow < 8; ++ow) {
            float r = rr[ow + kw];
            acc[0][ow] = fmaf(r, wv.x, acc[0][ow]);
            acc[1][ow] = fmaf(r, wv.y, acc[1][ow]);
            acc[2][ow] = fmaf(r, wv.z, acc[2][ow]);
            acc[3][ow] = fmaf(r, wv.w, acc[3][ow]);
          }
        }
      }
    }
  }
  const int oh = oh0 + oh_l;
  if (oh < H2) {
#pragma unroll
    for (int o = 0; o < 4; ++o) {
      int oc = oc0 + ocg * 4 + o;
      float bo = b3[oc];
      float* dst = &p3[((size_t)b * C3 + oc) * NN + oh * 8];
      *(float4*)dst       = make_float4(frelu(acc[o][0] + bo), frelu(acc[o][1] + bo),
                                        frelu(acc[o][2] + bo), frelu(acc[o][3] + bo));
      *(float4*)(dst + 4) = make_float4(frelu(acc[o][4] + bo), frelu(acc[o][5] + bo),
                                        frelu(acc[o][6] + bo), frelu(acc[o][7] + bo));
    }
  }
}

// ========== fused conv5a + conv5c (3x3, cin128 -> 32+32) + BN + ReLU ==========
// grid (65, 4), block 128. voc 0..31 -> feat1 (c5a), 32..63 -> feat2 (c5c).
__global__ __launch_bounds__(128) void k_c5(const float* __restrict__ p3,
                                            const float* __restrict__ wa,
                                            const float* __restrict__ sa5, const float* __restrict__ ba5,
                                            const float* __restrict__ ma5, const float* __restrict__ va5,
                                            const float* __restrict__ wc,
                                            const float* __restrict__ sc5, const float* __restrict__ bc5,
                                            const float* __restrict__ mc5, const float* __restrict__ vc5,
                                            float* __restrict__ f1, float* __restrict__ f2) {
  __shared__ __align__(16) float tin[8 * 10 * 12];  // 960
  __shared__ __align__(16) float twt[72 * 64];
  const int oh0 = blockIdx.x * 8;
  const int b   = blockIdx.y;
  const int tid = threadIdx.x;
  const int vocg = tid >> 3, oh_l = tid & 7;
  float acc[4][8] = {};
  for (int cc = 0; cc < 16; ++cc) {
    __syncthreads();
    for (int e = tid; e < 640; e += 128) {
      int ci = e / 80, r = e - ci * 80;
      int tr = r >> 3, c = r & 7;
      int ih = oh0 - 1 + tr;
      int cin = cc * 8 + ci;
      float v = 0.f;
      if (ih >= 0 && ih < H2) v = p3[((size_t)b * C3 + cin) * NN + ih * 8 + c];
      tin[(ci * 10 + tr) * 12 + c] = v;
    }
    for (int e = tid; e < 4608; e += 128) {
      int voc_l = e & 63, t = e >> 6;
      const float* base = (voc_l < 32) ? (wa + (size_t)voc_l * 1152) : (wc + (size_t)(voc_l - 32) * 1152);
      twt[t * 64 + voc_l] = base[cc * 8 * 9 + t];
    }
    __syncthreads();
#pragma unroll 1
    for (int ci = 0; ci < 8; ++ci) {
#pragma unroll
      for (int kh = 0; kh < 3; ++kh) {
        const float* rp = &tin[(ci * 10 + oh_l + kh) * 12];
        float4 a0 = *(const float4*)rp;
        float4 a1 = *(const float4*)(rp + 4);
        float rr[10];
        rr[0] = 0.f; rr[9] = 0.f;
        rr[1] = a0.x; rr[2] = a0.y; rr[3] = a0.z; rr[4] = a0.w;
        rr[5] = a1.x; rr[6] = a1.y; rr[7] = a1.z; rr[8] = a1.w;
#pragma unroll
        for (int kw = 0; kw < 3; ++kw) {
          float4 wv = *(const float4*)&twt[(ci * 9 + kh * 3 + kw) * 64 + vocg * 4];
#pragma unroll
          for (int ow = 0; ow < 8; ++ow) {
            float r = rr[ow + kw];
            acc[0][ow] = fmaf(r, wv.x, acc[0][ow]);
            acc[1][ow] = fmaf(r, wv.y, acc[1][ow]);
            acc[2][ow] = fmaf(r, wv.z, acc[2][ow]);
            acc[3][ow] = fmaf(r, wv.w, acc[3][ow]);
          }
        }
      }
    }
  }
  const int oh = oh0 + oh_l;
  if (oh < H2) {
#pragma unroll
    for (int vv = 0; vv < 4; ++vv) {
      int voc = vocg * 4 + vv;
      bool A = voc < 32;
      int ci = voc & 31;
      float sN = A ? sa5[ci] : sc5[ci];
      float bN = A ? ba5[ci] : bc5[ci];
      float mN = A ? ma5[ci] : mc5[ci];
      float vN = A ? va5[ci] : vc5[ci];
      float inv = sN * rsqrtf(vN + 1e-5f);
      float sh  = bN - mN * inv;
      float* dst = (A ? f1 : f2) + ((size_t)b * 32 + ci) * NN + oh * 8;
      float y[8];
#pragma unroll
      for (int ow = 0; ow < 8; ++ow) y[ow] = frelu(acc[vv][ow] * inv + sh);
      *(float4*)dst       = make_float4(y[0], y[1], y[2], y[3]);
      *(float4*)(dst + 4) = make_float4(y[4], y[5], y[6], y[7]);
    }
  }
}

// ================= 1x1 convs for q, k, v =================
// grid (17, 40, 4), block 256.  y: 0-3 q, 4-7 k, 8-39 v.
__global__ __launch_bounds__(256) void k_qkv(const float* __restrict__ f1,
                                             const float* __restrict__ qw, const float* __restrict__ qbv,
                                             const float* __restrict__ kwp, const float* __restrict__ kbv,
                                             const float* __restrict__ vwp, const float* __restrict__ vbv,
                                             float* __restrict__ qo, float* __restrict__ ko,
                                             float* __restrict__ vo) {
  const int n = blockIdx.x * 256 + threadIdx.x;
  if (n >= NN) return;
  const int ocv = blockIdx.y, b = blockIdx.z;
  const float* w;
  float bias;
  float* dst;
  if (ocv < 4)      { w = qw + ocv * 32;        bias = qbv[ocv];     dst = qo + ((size_t)b * 4 + ocv) * NN; }
  else if (ocv < 8) { int o = ocv - 4; w = kwp + o * 32; bias = kbv[o]; dst = ko + ((size_t)b * 4 + o) * NN; }
  else              { int o = ocv - 8; w = vwp + o * 32; bias = vbv[o]; dst = vo + ((size_t)b * 32 + o) * NN; }
  float a = bias;
#pragma unroll
  for (int c = 0; c < 32; ++c) a = fmaf(f1[((size_t)b * 32 + c) * NN + n], w[c], a);
  dst[n] = a;
}

// ================= flash PAM attention, partial (j-split x8) =================
__device__ __forceinline__ float rmax32(const float (&p)[32]) {
  float x0 = p[0], x1 = p[1], x2 = p[2], x3 = p[3];
#pragma unroll
  for (int j = 4; j < 32; j += 4) {
    x0 = fmaxf(x0, p[j]); x1 = fmaxf(x1, p[j + 1]);
    x2 = fmaxf(x2, p[j + 2]); x3 = fmaxf(x3, p[j + 3]);
  }
  return fmaxf(fmaxf(x0, x1), fmaxf(x2, x3));
}
__device__ __forceinline__ float rsum32(const float (&p)[32]) {
  float x0 = p[0], x1 = p[1], x2 = p[2], x3 = p[3];
#pragma unroll
  for (int j = 4; j < 32; j += 4) { x0 += p[j]; x1 += p[j + 1]; x2 += p[j + 2]; x3 += p[j + 3]; }
  return (x0 + x1) + (x2 + x3);
}

// grid (33, 8, 4), block 64.  Each lane owns rows i0+lane and i0+64+lane.
__global__ __launch_bounds__(64, 2) void k_flash(const float* __restrict__ qb,
                                                 const float* __restrict__ kb,
                                                 const float* __restrict__ vb,
                                                 float* __restrict__ accp,
                                                 float* __restrict__ mlb) {
  __shared__ __align__(16) float ks[4 * 32];
  __shared__ __align__(16) float vs[32 * 32];
  const int lane = threadIdx.x;
  const int i0 = blockIdx.x * 128;
  const int sp = blockIdx.y;
  const int b  = blockIdx.z;
  const int ia = i0 + lane, ib = i0 + 64 + lane;
  float qa[4], qd[4];
#pragma unroll
  for (int d = 0; d < 4; ++d) {
    qa[d] = (ia < NN) ? qb[((size_t)b * 4 + d) * NN + ia] : 0.f;
    qd[d] = (ib < NN) ? qb[((size_t)b * 4 + d) * NN + ib] : 0.f;
  }
  float ma = -1e30f, mb = -1e30f, la = 0.f, lb = 0.f;
  float acca[32], accb[32];
#pragma unroll
  for (int c = 0; c < 32; ++c) { acca[c] = 0.f; accb[c] = 0.f; }
  const int jbeg = sp * JSPAN;
  const int jend = (jbeg + JSPAN < NN) ? jbeg + JSPAN : NN;
  for (int j0 = jbeg; j0 < jend; j0 += 32) {
    const int nv = (jend - j0 < 32) ? jend - j0 : 32;
    __syncthreads();
    {
      int e = lane;
#pragma unroll
      for (int r = 0; r < 2; ++r, e += 64) {
        int d = e >> 5, j = e & 31;
        ks[e] = (j < nv) ? kb[((size_t)b * 4 + d) * NN + j0 + j] : 0.f;
      }
      e = lane;
#pragma unroll
      for (int r = 0; r < 16; ++r, e += 64) {
        int c = e >> 5, j = e & 31;
        vs[e] = (j < nv) ? vb[((size_t)b * 32 + c) * NN + j0 + j] : 0.f;
      }
    }
    __syncthreads();
    float pa[32], pb[32];
#pragma unroll
    for (int jj = 0; jj < 8; ++jj) {
      float4 k0 = *(const float4*)&ks[0 * 32 + 4 * jj];
      float4 k1 = *(const float4*)&ks[1 * 32 + 4 * jj];
      float4 k2 = *(const float4*)&ks[2 * 32 + 4 * jj];
      float4 k3 = *(const float4*)&ks[3 * 32 + 4 * jj];
      pa[4 * jj + 0] = fmaf(qa[0], k0.x, fmaf(qa[1], k1.x, fmaf(qa[2], k2.x, qa[3] * k3.x)));
      pa[4 * jj + 1] = fmaf(qa[0], k0.y, fmaf(qa[1], k1.y, fmaf(qa[2], k2.y, qa[3] * k3.y)));
      pa[4 * jj + 2] = fmaf(qa[0], k0.z, fmaf(qa[1], k1.z, fmaf(qa[2], k2.z, qa[3] * k3.z)));
      pa[4 * jj + 3] = fmaf(qa[0], k0.w, fmaf(qa[1], k1.w, fmaf(qa[2], k2.w, qa[3] * k3.w)));
      pb[4 * jj + 0] = fmaf(qd[0], k0.x, fmaf(qd[1], k1.x, fmaf(qd[2], k2.x, qd[3] * k3.x)));
      pb[4 * jj + 1] = fmaf(qd[0], k0.y, fmaf(qd[1], k1.y, fmaf(qd[2], k2.y, qd[3] * k3.y)));
      pb[4 * jj + 2] = fmaf(qd[0], k0.z, fmaf(qd[1], k1.z, fmaf(qd[2], k2.z, qd[3] * k3.z)));
      pb[4 * jj + 3] = fmaf(qd[0], k0.w, fmaf(qd[1], k1.w, fmaf(qd[2], k2.w, qd[3] * k3.w)));
    }
    if (nv < 32) {
#pragma unroll
      for (int j = 0; j < 32; ++j)
        if (j >= nv) { pa[j] = -1e30f; pb[j] = -1e30f; }
    }
    float mna = fmaxf(ma, rmax32(pa));
    float mnb = fmaxf(mb, rmax32(pb));
    float fa = __expf(ma - mna);
    float fb = __expf(mb - mnb);
    ma = mna; mb = mnb;
#pragma unroll
    for (int j = 0; j < 32; ++j) {
      pa[j] = __expf(pa[j] - mna);
      pb[j] = __expf(pb[j] - mnb);
    }
    la = fmaf(la, fa, rsum32(pa));
    lb = fmaf(lb, fb, rsum32(pb));
#pragma unroll
    for (int c = 0; c < 32; ++c) { acca[c] *= fa; accb[c] *= fb; }
#pragma unroll
    for (int jj = 0; jj < 8; ++jj) {
      float4 p4a = make_float4(pa[4 * jj], pa[4 * jj + 1], pa[4 * jj + 2], pa[4 * jj + 3]);
      float4 p4b = make_float4(pb[4 * jj], pb[4 * jj + 1], pb[4 * jj + 2], pb[4 * jj + 3]);
#pragma unroll
      for (int c = 0; c < 32; ++c) {
        float4 vv = *(const float4*)&vs[c * 32 + 4 * jj];
        acca[c] = fmaf(p4a.x, vv.x, fmaf(p4a.y, vv.y, fmaf(p4a.z, vv.z, fmaf(p4a.w, vv.w, acca[c]))));
        accb[c] = fmaf(p4b.x, vv.x, fmaf(p4b.y, vv.y, fmaf(p4b.z, vv.z, fmaf(p4b.w, vv.w, accb[c]))));
      }
    }
  }
  const size_t sb4 = (size_t)(sp * 4 + b);
#pragma unroll
  for (int c = 0; c < 32; ++c) {
    accp[(sb4 * 32 + c) * NPAD + ia] = acca[c];
    accp[(sb4 * 32 + c) * NPAD + ib] = accb[c];
  }
  mlb[(sb4 * 2 + 0) * NPAD + ia] = ma;
  mlb[(sb4 * 2 + 0) * NPAD + ib] = mb;
  mlb[(sb4 * 2 + 1) * NPAD + ia] = la;
  mlb[(sb4 * 2 + 1) * NPAD + ib] = lb;
}

// ================= combine flash partials -> sa = gamma*attn@v + feat1 ============
// grid (17, 32, 4), block 256.
__global__ __launch_bounds__(256) void k_combine(const float* __restrict__ accp,
                                                 const float* __restrict__ mlb,
                                                 const float* __restrict__ f1,
                                                 const float* __restrict__ gamma,
                                                 float* __restrict__ sa) {
  const int n = blockIdx.x * 256 + threadIdx.x;
  if (n >= NN) return;
  const int c = blockIdx.y, b = blockIdx.z;
  float m[8], l[8];
#pragma unroll
  for (int s = 0; s < 8; ++s) {
    m[s] = mlb[((size_t)(s * 4 + b) * 2 + 0) * NPAD + n];
    l[s] = mlb[((size_t)(s * 4 + b) * 2 + 1) * NPAD + n];
  }
  float ms = m[0];
#pragma unroll
  for (int s = 1; s < 8; ++s) ms = fmaxf(ms, m[s]);
  float den = 0.f, num = 0.f;
#pragma unroll
  for (int s = 0; s < 8; ++s) {
    float w = __expf(m[s] - ms);
    den = fmaf(l[s], w, den);
    num = fmaf(w, accp[((size_t)(s * 4 + b) * 32 + c) * NPAD + n], num);
  }
  size_t o = ((size_t)b * 32 + c) * NN + n;
  sa[o] = gamma[0] * num / den + f1[o];
}

// ================= CAM: energy (atomic partials) ==============================
__global__ __launch_bounds__(256) void k_zero(float* __restrict__ p) {
  int i = blockIdx.x * 256 + threadIdx.x;
  if (i < 4096) p[i] = 0.f;
}

// grid (17, 4), block 256.
__global__ __launch_bounds__(256) void k_energy(const float* __restrict__ f2,
                                                float* __restrict__ energy) {
  __shared__ float fs[32 * 257];
  const int n0 = blockIdx.x * 256, b = blockIdx.y, tid = threadIdx.x;
  for (int e = tid; e < 32 * 256; e += 256) {
    int c = e >> 8, nl = e & 255;
    int n = n0 + nl;
    fs[c * 257 + nl] = (n < NN) ? f2[((size_t)b * 32 + c) * NN + n] : 0.f;
  }
  __syncthreads();
  const int cg = tid >> 4, dg = tid & 15;
  const int c0 = cg * 2, d0 = dg * 2;
  float e00 = 0.f, e01 = 0.f, e10 = 0.f, e11 = 0.f;
  for (int t = 0; t < 256; ++t) {
    float a0 = fs[c0 * 257 + t], a1 = fs[(c0 + 1) * 257 + t];
    float b0 = fs[d0 * 257 + t], b1 = fs[(d0 + 1) * 257 + t];
    e00 = fmaf(a0, b0, e00); e01 = fmaf(a0, b1, e01);
    e10 = fmaf(a1, b0, e10); e11 = fmaf(a1, b1, e11);
  }
  float* eb = energy + b * 1024;
  atomicAdd(&eb[c0 * 32 + d0], e00);
  atomicAdd(&eb[c0 * 32 + d0 + 1], e01);
  atomicAdd(&eb[(c0 + 1) * 32 + d0], e10);
  atomicAdd(&eb[(c0 + 1) * 32 + d0 + 1], e11);
}

// ======== CAM apply: cattn = softmax(maxE - E) rows; sc = g*cattn@f2 + f2 ========
// grid (65, 4), block 64.
__global__ __launch_bounds__(64) void k_cam(const float* __restrict__ f2,
                                            const float* __restrict__ energy,
                                            const float* __restrict__ gamma,
                                            float* __restrict__ sc) {
  __shared__ __align__(16) float cat[32 * 32];
  const int lane = threadIdx.x, b = blockIdx.y;
  const int n = blockIdx.x * 64 + lane;
  if (lane < 32) {
    const float* eb = energy + b * 1024 + lane * 32;
    float e[32];
#pragma unroll
    for (int d = 0; d < 32; ++d) e[d] = eb[d];
    float mn = e[0];
#pragma unroll
    for (int d = 1; d < 32; ++d) mn = fminf(mn, e[d]);
    float w[32];
    float sum = 0.f;
#pragma unroll
    for (int d = 0; d < 32; ++d) { w[d] = __expf(mn - e[d]); sum += w[d]; }
    float inv = 1.f / sum;
#pragma unroll
    for (int d = 0; d < 32; ++d) cat[lane * 32 + d] = w[d] * inv;
  }
  __syncthreads();
  const bool ok = n < NN;
  float f[32];
#pragma unroll
  for (int c = 0; c < 32; ++c) f[c] = ok ? f2[((size_t)b * 32 + c) * NN + n] : 0.f;
  const float g = gamma[0];
#pragma unroll
  for (int c = 0; c < 32; ++c) {
    float a = 0.f;
#pragma unroll
    for (int k4 = 0; k4 < 8; ++k4) {
      float4 cw = *(const float4*)&cat[c * 32 + 4 * k4];
      a = fmaf(cw.x, f[4 * k4], fmaf(cw.y, f[4 * k4 + 1], fmaf(cw.z, f[4 * k4 + 2], fmaf(cw.w, f[4 * k4 + 3], a))));
    }
    if (ok) sc[((size_t)b * 32 + c) * NN + n] = g * a + f[c];
  }
}

// ======== fused c51(sa)+BN+ReLU, c52(sc)+BN+ReLU, sum, conv8 1x1 -> out ========
// grid (65, 4), block 128.
__global__ __launch_bounds__(128) void k_final(const float* __restrict__ sa,
                                               const float* __restrict__ sc,
                                               const float* __restrict__ w51,
                                               const float* __restrict__ s51, const float* __restrict__ b51,
                                               const float* __restrict__ m51, const float* __restrict__ v51,
                                               const float* __restrict__ w52,
                                               const float* __restrict__ s52, const float* __restrict__ b52,
                                               const float* __restrict__ m52, const float* __restrict__ v52,
                                               const float* __restrict__ w8, const float* __restrict__ b8,
                                               float* __restrict__ out) {
  __shared__ __align__(16) float tin[2 * 8 * 10 * 12];  // 1920
  __shared__ __align__(16) float twt[72 * 64];          // 4608
  __shared__ float tmid[64 * 65];
  const int oh0 = blockIdx.x * 8;
  const int b   = blockIdx.y;
  const int tid = threadIdx.x;
  const int vocg = tid >> 3, oh_l = tid & 7;
  float acc[4][8] = {};
  for (int cc = 0; cc < 4; ++cc) {
    __syncthreads();
    for (int e = tid; e < 1280; e += 128) {
      int which = (e >= 640) ? 1 : 0;
      int r1 = e - which * 640;
      int ci = r1 / 80, r2 = r1 - ci * 80;
      int tr = r2 >> 3, c = r2 & 7;
      int ih = oh0 - 1 + tr;
      int cin = cc * 8 + ci;
      const float* src = which ? sc : sa;
      float v = 0.f;
      if (ih >= 0 && ih < H2) v = src[((size_t)b * 32 + cin) * NN + ih * 8 + c];
      tin[which * 960 + (ci * 10 + tr) * 12 + c] = v;
    }
    for (int e = tid; e < 4608; e += 128) {
      int voc_l = e & 63, t = e >> 6;
      const float* base = (voc_l < 32) ? (w51 + voc_l * 288) : (w52 + (voc_l - 32) * 288);
      twt[t * 64 + voc_l] = base[cc * 8 * 9 + t];
    }
    __syncthreads();
    const float* tbase = tin + (vocg < 8 ? 0 : 960);
#pragma unroll 1
    for (int ci = 0; ci < 8; ++ci) {
#pragma unroll
      for (int kh = 0; kh < 3; ++kh) {
        const float* rp = tbase + (ci * 10 + oh_l + kh) * 12;
        float4 a0 = *(const float4*)rp;
        float4 a1 = *(const float4*)(rp + 4);
        float rr[10];
        rr[0] = 0.f; rr[9] = 0.f;
        rr[1] = a0.x; rr[2] = a0.y; rr[3] = a0.z; rr[4] = a0.w;
        rr[5] = a1.x; rr[6] = a1.y; rr[7] = a1.z; rr[8] = a1.w;
#pragma unroll
        for (int kw = 0; kw < 3; ++kw) {
          float4 wv = *(const float4*)&twt[(ci * 9 + kh * 3 + kw) * 64 + vocg * 4];
#pragma unroll
          for (int ow = 0; ow < 8; ++ow) {
            float r = rr[ow + kw];
            acc[0][ow] = fmaf(r, wv.x, acc[0][ow]);
            acc[1][ow] = fmaf(r, wv.y, acc[1][ow]);
            acc[2][ow] = fmaf(r, wv.z, acc[2][ow]);
            acc[3][ow] = fmaf(r, wv.w, acc[3][ow]);
          }
        }
      }
    }
  }
  {
    float inv[4], sh[4];
#pragma unroll
    for (int vv = 0; vv < 4; ++vv) {
      int voc = vocg * 4 + vv;
      bool A = voc < 32;
      int ci = voc & 31;
      float sN = A ? s51[ci] : s52[ci];
      float bN = A ? b51[ci] : b52[ci];
      float mN = A ? m51[ci] : m52[ci];
      float vN = A ? v51[ci] : v52[ci];
      inv[vv] = sN * rsqrtf(vN + 1e-5f);
      sh[vv] = bN - mN * inv[vv];
    }
#pragma unroll
    for (int ow = 0; ow < 8; ++ow) {
      int pos = oh_l * 8 + ow;
#pragma unroll
      for (int vv = 0; vv < 4; ++vv) {
        float y = acc[vv][ow] * inv[vv] + sh[vv];
        tmid[pos * 65 + vocg * 4 + vv] = frelu(y);
      }
    }
  }
  __syncthreads();
  {
    const int o = tid >> 6, pos = tid & 63;
    const int oh = oh0 + (pos >> 3), ow = pos & 7;
    float a = b8[o];
    const float* wrow = w8 + o * 32;
#pragma unroll
    for (int c = 0; c < 32; ++c)
      a = fmaf(tmid[pos * 65 + c] + tmid[pos * 65 + 32 + c], wrow[c], a);
    if (oh < H2) out[((size_t)b * 2 + o) * NN + oh * 8 + ow] = a;
  }
}

// =========================== launcher ===========================
extern "C" void kernel_launch(void* const* d_in, const int* in_sizes, int n_in,
                              void* d_out, int out_size, void* d_ws, size_t ws_size,
                              hipStream_t stream) {
  (void)in_sizes; (void)n_in; (void)out_size; (void)ws_size;
  const float* x      = (const float*)d_in[0];
  const float* w1     = (const float*)d_in[1];
  const float* b1     = (const float*)d_in[2];
  const float* w2     = (const float*)d_in[3];
  const float* b2     = (const float*)d_in[4];
  const float* w3     = (const float*)d_in[5];
  const float* b3     = (const float*)d_in[6];
  const float* c5a_w  = (const float*)d_in[7];
  const float* bn5a_s = (const float*)d_in[8];
  const float* bn5a_b = (const float*)d_in[9];
  const float* bn5a_m = (const float*)d_in[10];
  const float* bn5a_v = (const float*)d_in[11];
  const float* c5c_w  = (const float*)d_in[12];
  const float* bn5c_s = (const float*)d_in[13];
  const float* bn5c_b = (const float*)d_in[14];
  const float* bn5c_m = (const float*)d_in[15];
  const float* bn5c_v = (const float*)d_in[16];
  const float* c51_w  = (const float*)d_in[17];
  const float* bn51_s = (const float*)d_in[18];
  const float* bn51_b = (const float*)d_in[19];
  const float* bn51_m = (const float*)d_in[20];
  const float* bn51_v = (const float*)d_in[21];
  const float* c52_w  = (const float*)d_in[22];
  const float* bn52_s = (const float*)d_in[23];
  const float* bn52_b = (const float*)d_in[24];
  const float* bn52_m = (const float*)d_in[25];
  const float* bn52_v = (const float*)d_in[26];
  const float* pam_qw = (const float*)d_in[27];
  const float* pam_qb = (const float*)d_in[28];
  const float* pam_kw = (const float*)d_in[29];
  const float* pam_kb = (const float*)d_in[30];
  const float* pam_vw = (const float*)d_in[31];
  const float* pam_vb = (const float*)d_in[32];
  const float* pgamma = (const float*)d_in[33];
  const float* cgamma = (const float*)d_in[34];
  const float* c8_w   = (const float*)d_in[35];
  const float* c8_b   = (const float*)d_in[36];

  float* W    = (float*)d_ws;
  float* h1   = W + OFF_H1;
  float* p2   = W + OFF_P2;
  float* p3   = W + OFF_P3;
  float* f1   = W + OFF_F1;
  float* f2   = W + OFF_F2;
  float* qbuf = W + OFF_Q;
  float* kbuf = W + OFF_K;
  float* vbuf = W + OFF_V;
  float* sab  = W + OFF_SA;
  float* scb  = W + OFF_SC;
  float* accp = W + OFF_ACCP;
  float* mlb  = W + OFF_ML;
  float* enb  = W + OFF_EN;
  float* outp = (float*)d_out;

  k_conv1<<<dim3(65, 16, 4), 256, 0, stream>>>(x, w1, b1, h1);
  k_conv2<<<dim3(33, 4, 4), 128, 0, stream>>>(h1, w2, b2, p2);
  k_conv3<<<dim3(33, 4, 4), 128, 0, stream>>>(p2, w3, b3, p3);
  k_c5<<<dim3(65, 4), 128, 0, stream>>>(p3,
                                        c5a_w, bn5a_s, bn5a_b, bn5a_m, bn5a_v,
                                        c5c_w, bn5c_s, bn5c_b, bn5c_m, bn5c_v,
                                        f1, f2);
  k_qkv<<<dim3(17, 40, 4), 256, 0, stream>>>(f1, pam_qw, pam_qb, pam_kw, pam_kb,
                                             pam_vw, pam_vb, qbuf, kbuf, vbuf);
  k_zero<<<dim3(16), 256, 0, stream>>>(enb);
  k_flash<<<dim3(33, 8, 4), 64, 0, stream>>>(qbuf, kbuf, vbuf, accp, mlb);
  k_energy<<<dim3(17, 4), 256, 0, stream>>>(f2, enb);
  k_combine<<<dim3(17, 32, 4), 256, 0, stream>>>(accp, mlb, f1, pgamma, sab);
  k_cam<<<dim3(65, 4), 64, 0, stream>>>(f2, enb, cgamma, scb);
  k_final<<<dim3(65, 4), 128, 0, stream>>>(sab, scb,
                                           c51_w, bn51_s, bn51_b, bn51_m, bn51_v,
                                           c52_w, bn52_s, bn52_b, bn52_m, bn52_v,
                                           c8_w, c8_b, outp);
}

// Round 3
// 2082.641 us; speedup vs baseline: 1.6722x; 1.6722x over previous
//
#include <hip/hip_runtime.h>
#include <cstddef>

// ---------------- problem dims ----------------
constexpr int BB   = 4;
constexpr int LX   = 126975;
constexpr int H0   = 4096, W0 = 61;          // c_in spatial
constexpr int C1   = 128, H1 = 1025, W1 = 16;
constexpr int C2   = 256, H2 = 513,  W2 = 8;
constexpr int C3   = 128;
constexpr int NN   = H2 * W2;                // 4104
constexpr int NSPLIT = 15;                   // attention j-splits
constexpr int JSPAN  = 288;                  // 32-aligned; 15*288 >= 4104
constexpr int NPAD   = 4104;                 // partial-row stride (16B-aligned)

// ---------------- workspace layout (float offsets), lifetime-overlapped ----
// Region A [0, 8,396,800): h1 (conv1->conv2); p3 (conv3->c5) at 0;
//   after c5, accp/ml (flash->combine) reuse the whole region.
// Region B [8,396,800, +4,202,496): p2 (conv2->conv3); then f1,f2,q,k,v,sa,sc.
// Total = 12,603,392 floats = 50.4 MB.
constexpr size_t SZ_H1    = (size_t)BB * C1 * H1 * W1;        // 8,396,800
constexpr size_t SZ_P2    = (size_t)BB * C2 * NN;             // 4,202,496
constexpr size_t SZ_F     = (size_t)BB * 32 * NN;             //   525,312
constexpr size_t SZ_QK    = (size_t)BB * 4 * NN;              //    65,664
constexpr size_t SZ_ACCP  = (size_t)NSPLIT * BB * 32 * NPAD;  // 7,879,680
constexpr size_t SZ_ML    = (size_t)NSPLIT * BB * 2 * NPAD;   //   492,480

constexpr size_t OFF_H1   = 0;
constexpr size_t OFF_P3   = 0;                  // reuses h1 (dead after conv2)
constexpr size_t OFF_ACCP = 0;                  // reuses p3 (dead after c5)
constexpr size_t OFF_ML   = OFF_ACCP + SZ_ACCP; // ends 8,372,160 < 8,396,800
constexpr size_t RB       = SZ_H1;              // 8,396,800
constexpr size_t OFF_P2   = RB;
constexpr size_t OFF_F1   = RB;                 // reuses p2 (dead after conv3)
constexpr size_t OFF_F2   = OFF_F1 + SZ_F;
constexpr size_t OFF_Q    = OFF_F2 + SZ_F;
constexpr size_t OFF_K    = OFF_Q  + SZ_QK;
constexpr size_t OFF_V    = OFF_K  + SZ_QK;
constexpr size_t OFF_SA   = OFF_V  + SZ_F;
constexpr size_t OFF_SC   = OFF_SA + SZ_F;      // ends RB+2,757,888 < RB+4,202,496
constexpr size_t OFF_EN   = RB + SZ_P2;         // 4096 floats

__device__ __forceinline__ float frelu(float x) { return x > 0.f ? x : 0.f; }

// ================= conv1: 8x8 s4 p4, cin=1, 128 oc, +bias+relu ================
// grid (65, 16, 4), block 256.  Input gather (unfold+reshape) fused into staging.
__global__ __launch_bounds__(256) void k_conv1(const float* __restrict__ x,
                                               const float* __restrict__ w1,
                                               const float* __restrict__ b1,
                                               float* __restrict__ h1) {
  __shared__ __align__(16) float tile[68 * 68];
  const int oh0 = blockIdx.x * 16;
  const int oc0 = blockIdx.y * 8;
  const int b   = blockIdx.z;
  const int tid = threadIdx.x;
  const int ih0 = oh0 * 4 - 4;
  for (int e = tid; e < 68 * 68; e += 256) {
    int row = e / 68, col = e - row * 68;
    int ih = ih0 + row, iw = col - 4;
    float v = 0.f;
    if (ih >= 0 && ih < H0 && iw >= 0 && iw < W0) {
      int l   = ih * W0 + iw;
      int pos = (l >> 12) * 2048 + (l & 4095);
      if (pos < LX) v = x[(size_t)b * LX + pos];
    }
    tile[e] = v;
  }
  __syncthreads();
  const int oh_l = tid >> 4, ow = tid & 15;
  float acc[8];
#pragma unroll
  for (int o = 0; o < 8; ++o) acc[o] = 0.f;
#pragma unroll
  for (int kh = 0; kh < 8; ++kh) {
    const float* rp = &tile[(4 * oh_l + kh) * 68 + 4 * ow];
    float4 a0 = *(const float4*)rp;
    float4 a1 = *(const float4*)(rp + 4);
    float r[8] = {a0.x, a0.y, a0.z, a0.w, a1.x, a1.y, a1.z, a1.w};
#pragma unroll
    for (int kw = 0; kw < 8; ++kw) {
#pragma unroll
      for (int o = 0; o < 8; ++o)
        acc[o] = fmaf(r[kw], w1[(oc0 + o) * 64 + kh * 8 + kw], acc[o]);
    }
  }
  const int oh = oh0 + oh_l;
  if (oh < H1) {
#pragma unroll
    for (int o = 0; o < 8; ++o) {
      float v = frelu(acc[o] + b1[oc0 + o]);
      h1[(((size_t)b * C1 + oc0 + o) * H1 + oh) * W1 + ow] = v;
    }
  }
}

// ================= conv2: 5x5 s2 p2, full cin 128, +bias+relu ================
// grid (33, 4, 4).  block 128: thread = 8oc x 8ow, 16 oh rows.
__global__ __launch_bounds__(128) void k_conv2(const float* __restrict__ h1,
                                               const float* __restrict__ w2,
                                               const float* __restrict__ b2,
                                               float* __restrict__ p2) {
  constexpr int S = 20;
  __shared__ __align__(16) float tin[4 * 35 * S];   // 2800
  __shared__ __align__(16) float twt[100 * 64];     // 6400
  const int oh0  = blockIdx.x * 16;
  const int oc0  = blockIdx.y * 64;
  const int b    = blockIdx.z;
  const int tid  = threadIdx.x;
  const int oh_l = tid & 15, ocg = tid >> 4;
  float acc[8][8] = {};
  for (int cc = 0; cc < 32; ++cc) {
    __syncthreads();
    for (int e = tid; e < 4 * 35 * 16; e += 128) {
      int ci = e / 560, r = e - ci * 560;
      int tr = r >> 4, c = r & 15;
      int ih = oh0 * 2 - 2 + tr;
      int cin = cc * 4 + ci;
      float v = 0.f;
      if (ih >= 0 && ih < H1) v = h1[(((size_t)b * C1 + cin) * H1 + ih) * W1 + c];
      tin[(ci * 35 + tr) * S + c] = v;
    }
    for (int e = tid; e < 6400; e += 128) {
      int oc_l = e & 63, t = e >> 6;
      twt[t * 64 + oc_l] = w2[(size_t)(oc0 + oc_l) * 3200 + cc * 100 + t];
    }
    __syncthreads();
#pragma unroll 1
    for (int ci = 0; ci < 4; ++ci) {
#pragma unroll
      for (int kh = 0; kh < 5; ++kh) {
        const float* rp = &tin[(ci * 35 + 2 * oh_l + kh) * S];
        float4 a0 = *(const float4*)rp;
        float4 a1 = *(const float4*)(rp + 4);
        float4 a2 = *(const float4*)(rp + 8);
        float4 a3 = *(const float4*)(rp + 12);
        float rr[19];
        rr[0] = 0.f; rr[1] = 0.f; rr[18] = 0.f;
        rr[2] = a0.x; rr[3] = a0.y; rr[4] = a0.z; rr[5] = a0.w;
        rr[6] = a1.x; rr[7] = a1.y; rr[8] = a1.z; rr[9] = a1.w;
        rr[10] = a2.x; rr[11] = a2.y; rr[12] = a2.z; rr[13] = a2.w;
        rr[14] = a3.x; rr[15] = a3.y; rr[16] = a3.z; rr[17] = a3.w;
#pragma unroll
        for (int kw = 0; kw < 5; ++kw) {
          const float* wp = &twt[(ci * 25 + kh * 5 + kw) * 64 + ocg * 8];
          float4 w0 = *(const float4*)wp;
          float4 w1v = *(const float4*)(wp + 4);
          float wv[8] = {w0.x, w0.y, w0.z, w0.w, w1v.x, w1v.y, w1v.z, w1v.w};
#pragma unroll
          for (int o = 0; o < 8; ++o)
#pragma unroll
            for (int ow = 0; ow < 8; ++ow)
              acc[o][ow] = fmaf(rr[2 * ow + kw], wv[o], acc[o][ow]);
        }
      }
    }
  }
  const int oh = oh0 + oh_l;
  if (oh < H2) {
#pragma unroll
    for (int o = 0; o < 8; ++o) {
      int oc = oc0 + ocg * 8 + o;
      float bo = b2[oc];
      float* dst = &p2[((size_t)b * C2 + oc) * NN + oh * 8];
      *(float4*)dst       = make_float4(frelu(acc[o][0] + bo), frelu(acc[o][1] + bo),
                                        frelu(acc[o][2] + bo), frelu(acc[o][3] + bo));
      *(float4*)(dst + 4) = make_float4(frelu(acc[o][4] + bo), frelu(acc[o][5] + bo),
                                        frelu(acc[o][6] + bo), frelu(acc[o][7] + bo));
    }
  }
}

// ================= conv3: 3x3 s1 p1, full cin 256, +bias+relu ================
// grid (33, 4, 4): y = 32-oc chunk.  block 128: 16 oh x (8 grp x 4 oc).
__global__ __launch_bounds__(128) void k_conv3(const float* __restrict__ p2,
                                               const float* __restrict__ w3,
                                               const float* __restrict__ b3,
                                               float* __restrict__ p3) {
  __shared__ __align__(16) float tin[8 * 18 * 12];  // 1728
  __shared__ __align__(16) float twt[72 * 32];      // 2304
  const int oh0 = blockIdx.x * 16;
  const int oc0 = blockIdx.y * 32;
  const int b   = blockIdx.z;
  const int tid = threadIdx.x;
  const int oh_l = tid & 15, ocg = tid >> 4;
  float acc[4][8] = {};
  for (int cc = 0; cc < 32; ++cc) {
    __syncthreads();
    for (int e = tid; e < 1152; e += 128) {
      int ci = e / 144, r = e - ci * 144;
      int tr = r >> 3, c = r & 7;
      int ih = oh0 - 1 + tr;
      int cin = cc * 8 + ci;
      float v = 0.f;
      if (ih >= 0 && ih < H2) v = p2[((size_t)b * C2 + cin) * NN + ih * 8 + c];
      tin[(ci * 18 + tr) * 12 + c] = v;
    }
    for (int e = tid; e < 2304; e += 128) {
      int oc_l = e & 31, t = e >> 5;
      twt[t * 32 + oc_l] = w3[(size_t)(oc0 + oc_l) * 2304 + cc * 72 + t];
    }
    __syncthreads();
#pragma unroll 1
    for (int ci = 0; ci < 8; ++ci) {
#pragma unroll
      for (int kh = 0; kh < 3; ++kh) {
        const float* rp = &tin[(ci * 18 + oh_l + kh) * 12];
        float4 a0 = *(const float4*)rp;
        float4 a1 = *(const float4*)(rp + 4);
        float rr[10];
        rr[0] = 0.f; rr[9] = 0.f;
        rr[1] = a0.x; rr[2] = a0.y; rr[3] = a0.z; rr[4] = a0.w;
        rr[5] = a1.x; rr[6] = a1.y; rr[7] = a1.z; rr[8] = a1.w;
#pragma unroll
        for (int kw = 0; kw < 3; ++kw) {
          float4 wv = *(const float4*)&twt[(ci * 9 + kh * 3 + kw) * 32 + ocg * 4];
#pragma unroll
          for (int ow = 0; ow < 8; ++ow) {
            float r = rr[ow + kw];
            acc[0][ow] = fmaf(r, wv.x, acc[0][ow]);
            acc[1][ow] = fmaf(r, wv.y, acc[1][ow]);
            acc[2][ow] = fmaf(r, wv.z, acc[2][ow]);
            acc[3][ow] = fmaf(r, wv.w, acc[3][ow]);
          }
        }
      }
    }
  }
  const int oh = oh0 + oh_l;
  if (oh < H2) {
#pragma unroll
    for (int o = 0; o < 4; ++o) {
      int oc = oc0 + ocg * 4 + o;
      float bo = b3[oc];
      float* dst = &p3[((size_t)b * C3 + oc) * NN + oh * 8];
      *(float4*)dst       = make_float4(frelu(acc[o][0] + bo), frelu(acc[o][1] + bo),
                                        frelu(acc[o][2] + bo), frelu(acc[o][3] + bo));
      *(float4*)(dst + 4) = make_float4(frelu(acc[o][4] + bo), frelu(acc[o][5] + bo),
                                        frelu(acc[o][6] + bo), frelu(acc[o][7] + bo));
    }
  }
}

// ========== fused conv5a + conv5c (3x3, cin128 -> 32+32) + BN + ReLU ==========
// grid (65, 4), block 128. voc 0..31 -> feat1 (c5a), 32..63 -> feat2 (c5c).
__global__ __launch_bounds__(128) void k_c5(const float* __restrict__ p3,
                                            const float* __restrict__ wa,
                                            const float* __restrict__ sa5, const float* __restrict__ ba5,
                                            const float* __restrict__ ma5, const float* __restrict__ va5,
                                            const float* __restrict__ wc,
                                            const float* __restrict__ sc5, const float* __restrict__ bc5,
                                            const float* __restrict__ mc5, const float* __restrict__ vc5,
                                            float* __restrict__ f1, float* __restrict__ f2) {
  __shared__ __align__(16) float tin[8 * 10 * 12];  // 960
  __shared__ __align__(16) float twt[72 * 64];
  const int oh0 = blockIdx.x * 8;
  const int b   = blockIdx.y;
  const int tid = threadIdx.x;
  const int vocg = tid >> 3, oh_l = tid & 7;
  float acc[4][8] = {};
  for (int cc = 0; cc < 16; ++cc) {
    __syncthreads();
    for (int e = tid; e < 640; e += 128) {
      int ci = e / 80, r = e - ci * 80;
      int tr = r >> 3, c = r & 7;
      int ih = oh0 - 1 + tr;
      int cin = cc * 8 + ci;
      float v = 0.f;
      if (ih >= 0 && ih < H2) v = p3[((size_t)b * C3 + cin) * NN + ih * 8 + c];
      tin[(ci * 10 + tr) * 12 + c] = v;
    }
    for (int e = tid; e < 4608; e += 128) {
      int voc_l = e & 63, t = e >> 6;
      const float* base = (voc_l < 32) ? (wa + (size_t)voc_l * 1152) : (wc + (size_t)(voc_l - 32) * 1152);
      twt[t * 64 + voc_l] = base[cc * 8 * 9 + t];
    }
    __syncthreads();
#pragma unroll 1
    for (int ci = 0; ci < 8; ++ci) {
#pragma unroll
      for (int kh = 0; kh < 3; ++kh) {
        const float* rp = &tin[(ci * 10 + oh_l + kh) * 12];
        float4 a0 = *(const float4*)rp;
        float4 a1 = *(const float4*)(rp + 4);
        float rr[10];
        rr[0] = 0.f; rr[9] = 0.f;
        rr[1] = a0.x; rr[2] = a0.y; rr[3] = a0.z; rr[4] = a0.w;
        rr[5] = a1.x; rr[6] = a1.y; rr[7] = a1.z; rr[8] = a1.w;
#pragma unroll
        for (int kw = 0; kw < 3; ++kw) {
          float4 wv = *(const float4*)&twt[(ci * 9 + kh * 3 + kw) * 64 + vocg * 4];
#pragma unroll
          for (int ow = 0; ow < 8; ++ow) {
            float r = rr[ow + kw];
            acc[0][ow] = fmaf(r, wv.x, acc[0][ow]);
            acc[1][ow] = fmaf(r, wv.y, acc[1][ow]);
            acc[2][ow] = fmaf(r, wv.z, acc[2][ow]);
            acc[3][ow] = fmaf(r, wv.w, acc[3][ow]);
          }
        }
      }
    }
  }
  const int oh = oh0 + oh_l;
  if (oh < H2) {
#pragma unroll
    for (int vv = 0; vv < 4; ++vv) {
      int voc = vocg * 4 + vv;
      bool A = voc < 32;
      int ci = voc & 31;
      float sN = A ? sa5[ci] : sc5[ci];
      float bN = A ? ba5[ci] : bc5[ci];
      float mN = A ? ma5[ci] : mc5[ci];
      float vN = A ? va5[ci] : vc5[ci];
      float inv = sN * rsqrtf(vN + 1e-5f);
      float sh  = bN - mN * inv;
      float* dst = (A ? f1 : f2) + ((size_t)b * 32 + ci) * NN + oh * 8;
      float y[8];
#pragma unroll
      for (int ow = 0; ow < 8; ++ow) y[ow] = frelu(acc[vv][ow] * inv + sh);
      *(float4*)dst       = make_float4(y[0], y[1], y[2], y[3]);
      *(float4*)(dst + 4) = make_float4(y[4], y[5], y[6], y[7]);
    }
  }
}

// ================= 1x1 convs for q, k, v =================
// grid (17, 40, 4), block 256.  y: 0-3 q, 4-7 k, 8-39 v.
__global__ __launch_bounds__(256) void k_qkv(const float* __restrict__ f1,
                                             const float* __restrict__ qw, const float* __restrict__ qbv,
                                             const float* __restrict__ kwp, const float* __restrict__ kbv,
                                             const float* __restrict__ vwp, const float* __restrict__ vbv,
                                             float* __restrict__ qo, float* __restrict__ ko,
                                             float* __restrict__ vo) {
  const int n = blockIdx.x * 256 + threadIdx.x;
  if (n >= NN) return;
  const int ocv = blockIdx.y, b = blockIdx.z;
  const float* w;
  float bias;
  float* dst;
  if (ocv < 4)      { w = qw + ocv * 32;        bias = qbv[ocv];     dst = qo + ((size_t)b * 4 + ocv) * NN; }
  else if (ocv < 8) { int o = ocv - 4; w = kwp + o * 32; bias = kbv[o]; dst = ko + ((size_t)b * 4 + o) * NN; }
  else              { int o = ocv - 8; w = vwp + o * 32; bias = vbv[o]; dst = vo + ((size_t)b * 32 + o) * NN; }
  float a = bias;
#pragma unroll
  for (int c = 0; c < 32; ++c) a = fmaf(f1[((size_t)b * 32 + c) * NN + n], w[c], a);
  dst[n] = a;
}

// ================= flash PAM attention, partial (j-split x15) =================
__device__ __forceinline__ float rmax32(const float (&p)[32]) {
  float x0 = p[0], x1 = p[1], x2 = p[2], x3 = p[3];
#pragma unroll
  for (int j = 4; j < 32; j += 4) {
    x0 = fmaxf(x0, p[j]); x1 = fmaxf(x1, p[j + 1]);
    x2 = fmaxf(x2, p[j + 2]); x3 = fmaxf(x3, p[j + 3]);
  }
  return fmaxf(fmaxf(x0, x1), fmaxf(x2, x3));
}
__device__ __forceinline__ float rsum32(const float (&p)[32]) {
  float x0 = p[0], x1 = p[1], x2 = p[2], x3 = p[3];
#pragma unroll
  for (int j = 4; j < 32; j += 4) { x0 += p[j]; x1 += p[j + 1]; x2 += p[j + 2]; x3 += p[j + 3]; }
  return (x0 + x1) + (x2 + x3);
}

// grid (17, 15, 4), block 256 (4 waves).  Thread owns row ia = bx*256 + tid.
// All four waves share the K (4x32) / V (32x32) LDS tiles; staging is one
// float4 global load per thread (fully coalesced, 16B-aligned since j0 % 32 == 0).
__global__ __launch_bounds__(256) void k_flash(const float* __restrict__ qb,
                                               const float* __restrict__ kb,
                                               const float* __restrict__ vb,
                                               float* __restrict__ accp,
                                               float* __restrict__ mlb) {
  __shared__ __align__(16) float ks[4 * 32];
  __shared__ __align__(16) float vs[32 * 32];
  const int tid = threadIdx.x;
  const int ia  = blockIdx.x * 256 + tid;
  const int sp  = blockIdx.y;
  const int b   = blockIdx.z;
  float q[4];
#pragma unroll
  for (int d = 0; d < 4; ++d)
    q[d] = (ia < NN) ? qb[((size_t)b * 4 + d) * NN + ia] : 0.f;
  float m = -1e30f, l = 0.f;
  float acc[32];
#pragma unroll
  for (int c = 0; c < 32; ++c) acc[c] = 0.f;
  const int jbeg = sp * JSPAN;
  const int jend = (jbeg + JSPAN < NN) ? jbeg + JSPAN : NN;
  const int cs = tid >> 3, j4 = (tid & 7) * 4;   // staging coords
  for (int j0 = jbeg; j0 < jend; j0 += 32) {
    const int nv = (jend - j0 < 32) ? jend - j0 : 32;
    __syncthreads();
    {
      const float* vsrc = &vb[((size_t)b * 32 + cs) * NN + j0 + j4];
      float4 v4;
      if (j4 + 4 <= nv) {
        v4 = *(const float4*)vsrc;
      } else {
        v4.x = (j4 + 0 < nv) ? vsrc[0] : 0.f;
        v4.y = (j4 + 1 < nv) ? vsrc[1] : 0.f;
        v4.z = (j4 + 2 < nv) ? vsrc[2] : 0.f;
        v4.w = (j4 + 3 < nv) ? vsrc[3] : 0.f;
      }
      *(float4*)&vs[cs * 32 + j4] = v4;
      if (tid < 32) {
        const int d = tid >> 3;
        const float* ksrc = &kb[((size_t)b * 4 + d) * NN + j0 + j4];
        float4 k4;
        if (j4 + 4 <= nv) {
          k4 = *(const float4*)ksrc;
        } else {
          k4.x = (j4 + 0 < nv) ? ksrc[0] : 0.f;
          k4.y = (j4 + 1 < nv) ? ksrc[1] : 0.f;
          k4.z = (j4 + 2 < nv) ? ksrc[2] : 0.f;
          k4.w = (j4 + 3 < nv) ? ksrc[3] : 0.f;
        }
        *(float4*)&ks[d * 32 + j4] = k4;
      }
    }
    __syncthreads();
    float p[32];
#pragma unroll
    for (int jj = 0; jj < 8; ++jj) {
      float4 k0 = *(const float4*)&ks[0 * 32 + 4 * jj];
      float4 k1 = *(const float4*)&ks[1 * 32 + 4 * jj];
      float4 k2 = *(const float4*)&ks[2 * 32 + 4 * jj];
      float4 k3 = *(const float4*)&ks[3 * 32 + 4 * jj];
      p[4 * jj + 0] = fmaf(q[0], k0.x, fmaf(q[1], k1.x, fmaf(q[2], k2.x, q[3] * k3.x)));
      p[4 * jj + 1] = fmaf(q[0], k0.y, fmaf(q[1], k1.y, fmaf(q[2], k2.y, q[3] * k3.y)));
      p[4 * jj + 2] = fmaf(q[0], k0.z, fmaf(q[1], k1.z, fmaf(q[2], k2.z, q[3] * k3.z)));
      p[4 * jj + 3] = fmaf(q[0], k0.w, fmaf(q[1], k1.w, fmaf(q[2], k2.w, q[3] * k3.w)));
    }
    if (nv < 32) {
#pragma unroll
      for (int j = 0; j < 32; ++j)
        if (j >= nv) p[j] = -1e30f;
    }
    float mn = fmaxf(m, rmax32(p));
    float f = __expf(m - mn);
    m = mn;
#pragma unroll
    for (int j = 0; j < 32; ++j) p[j] = __expf(p[j] - mn);
    l = fmaf(l, f, rsum32(p));
#pragma unroll
    for (int c = 0; c < 32; ++c) acc[c] *= f;
#pragma unroll
    for (int jj = 0; jj < 8; ++jj) {
      float4 p4 = make_float4(p[4 * jj], p[4 * jj + 1], p[4 * jj + 2], p[4 * jj + 3]);
#pragma unroll
      for (int c = 0; c < 32; ++c) {
        float4 vv = *(const float4*)&vs[c * 32 + 4 * jj];
        acc[c] = fmaf(p4.x, vv.x, fmaf(p4.y, vv.y, fmaf(p4.z, vv.z, fmaf(p4.w, vv.w, acc[c]))));
      }
    }
  }
  if (ia < NN) {
    const size_t sb4 = (size_t)(sp * 4 + b);
#pragma unroll
    for (int c = 0; c < 32; ++c)
      accp[(sb4 * 32 + c) * NPAD + ia] = acc[c];
    mlb[(sb4 * 2 + 0) * NPAD + ia] = m;
    mlb[(sb4 * 2 + 1) * NPAD + ia] = l;
  }
}

// ================= combine flash partials -> sa = gamma*attn@v + feat1 ============
// grid (17, 32, 4), block 256.
__global__ __launch_bounds__(256) void k_combine(const float* __restrict__ accp,
                                                 const float* __restrict__ mlb,
                                                 const float* __restrict__ f1,
                                                 const float* __restrict__ gamma,
                                                 float* __restrict__ sa) {
  const int n = blockIdx.x * 256 + threadIdx.x;
  if (n >= NN) return;
  const int c = blockIdx.y, b = blockIdx.z;
  float m[NSPLIT], l[NSPLIT];
#pragma unroll
  for (int s = 0; s < NSPLIT; ++s) {
    m[s] = mlb[((size_t)(s * 4 + b) * 2 + 0) * NPAD + n];
    l[s] = mlb[((size_t)(s * 4 + b) * 2 + 1) * NPAD + n];
  }
  float ms = m[0];
#pragma unroll
  for (int s = 1; s < NSPLIT; ++s) ms = fmaxf(ms, m[s]);
  float den = 0.f, num = 0.f;
#pragma unroll
  for (int s = 0; s < NSPLIT; ++s) {
    float w = __expf(m[s] - ms);
    den = fmaf(l[s], w, den);
    num = fmaf(w, accp[((size_t)(s * 4 + b) * 32 + c) * NPAD + n], num);
  }
  size_t o = ((size_t)b * 32 + c) * NN + n;
  sa[o] = gamma[0] * num / den + f1[o];
}

// ================= CAM: energy (atomic partials) ==============================
__global__ __launch_bounds__(256) void k_zero(float* __restrict__ p) {
  int i = blockIdx.x * 256 + threadIdx.x;
  if (i < 4096) p[i] = 0.f;
}

// grid (17, 4), block 256.
__global__ __launch_bounds__(256) void k_energy(const float* __restrict__ f2,
                                                float* __restrict__ energy) {
  __shared__ float fs[32 * 257];
  const int n0 = blockIdx.x * 256, b = blockIdx.y, tid = threadIdx.x;
  for (int e = tid; e < 32 * 256; e += 256) {
    int c = e >> 8, nl = e & 255;
    int n = n0 + nl;
    fs[c * 257 + nl] = (n < NN) ? f2[((size_t)b * 32 + c) * NN + n] : 0.f;
  }
  __syncthreads();
  const int cg = tid >> 4, dg = tid & 15;
  const int c0 = cg * 2, d0 = dg * 2;
  float e00 = 0.f, e01 = 0.f, e10 = 0.f, e11 = 0.f;
  for (int t = 0; t < 256; ++t) {
    float a0 = fs[c0 * 257 + t], a1 = fs[(c0 + 1) * 257 + t];
    float b0 = fs[d0 * 257 + t], b1 = fs[(d0 + 1) * 257 + t];
    e00 = fmaf(a0, b0, e00); e01 = fmaf(a0, b1, e01);
    e10 = fmaf(a1, b0, e10); e11 = fmaf(a1, b1, e11);
  }
  float* eb = energy + b * 1024;
  atomicAdd(&eb[c0 * 32 + d0], e00);
  atomicAdd(&eb[c0 * 32 + d0 + 1], e01);
  atomicAdd(&eb[(c0 + 1) * 32 + d0], e10);
  atomicAdd(&eb[(c0 + 1) * 32 + d0 + 1], e11);
}

// ======== CAM apply: cattn = softmax(maxE - E) rows; sc = g*cattn@f2 + f2 ========
// grid (65, 4), block 64.
__global__ __launch_bounds__(64) void k_cam(const float* __restrict__ f2,
                                            const float* __restrict__ energy,
                                            const float* __restrict__ gamma,
                                            float* __restrict__ sc) {
  __shared__ __align__(16) float cat[32 * 32];
  const int lane = threadIdx.x, b = blockIdx.y;
  const int n = blockIdx.x * 64 + lane;
  if (lane < 32) {
    const float* eb = energy + b * 1024 + lane * 32;
    float e[32];
#pragma unroll
    for (int d = 0; d < 32; ++d) e[d] = eb[d];
    float mn = e[0];
#pragma unroll
    for (int d = 1; d < 32; ++d) mn = fminf(mn, e[d]);
    float w[32];
    float sum = 0.f;
#pragma unroll
    for (int d = 0; d < 32; ++d) { w[d] = __expf(mn - e[d]); sum += w[d]; }
    float inv = 1.f / sum;
#pragma unroll
    for (int d = 0; d < 32; ++d) cat[lane * 32 + d] = w[d] * inv;
  }
  __syncthreads();
  const bool ok = n < NN;
  float f[32];
#pragma unroll
  for (int c = 0; c < 32; ++c) f[c] = ok ? f2[((size_t)b * 32 + c) * NN + n] : 0.f;
  const float g = gamma[0];
#pragma unroll
  for (int c = 0; c < 32; ++c) {
    float a = 0.f;
#pragma unroll
    for (int k4 = 0; k4 < 8; ++k4) {
      float4 cw = *(const float4*)&cat[c * 32 + 4 * k4];
      a = fmaf(cw.x, f[4 * k4], fmaf(cw.y, f[4 * k4 + 1], fmaf(cw.z, f[4 * k4 + 2], fmaf(cw.w, f[4 * k4 + 3], a))));
    }
    if (ok) sc[((size_t)b * 32 + c) * NN + n] = g * a + f[c];
  }
}

// ======== fused c51(sa)+BN+ReLU, c52(sc)+BN+ReLU, sum, conv8 1x1 -> out ========
// grid (65, 4), block 128.
__global__ __launch_bounds__(128) void k_final(const float* __restrict__ sa,
                                               const float* __restrict__ sc,
                                               const float* __restrict__ w51,
                                               const float* __restrict__ s51, const float* __restrict__ b51,
                                               const float* __restrict__ m51, const float* __restrict__ v51,
                                               const float* __restrict__ w52,
                                               const float* __restrict__ s52, const float* __restrict__ b52,
                                               const float* __restrict__ m52, const float* __restrict__ v52,
                                               const float* __restrict__ w8, const float* __restrict__ b8,
                                               float* __restrict__ out) {
  __shared__ __align__(16) float tin[2 * 8 * 10 * 12];  // 1920
  __shared__ __align__(16) float twt[72 * 64];          // 4608
  __shared__ float tmid[64 * 65];
  const int oh0 = blockIdx.x * 8;
  const int b   = blockIdx.y;
  const int tid = threadIdx.x;
  const int vocg = tid >> 3, oh_l = tid & 7;
  float acc[4][8] = {};
  for (int cc = 0; cc < 4; ++cc) {
    __syncthreads();
    for (int e = tid; e < 1280; e += 128) {
      int which = (e >= 640) ? 1 : 0;
      int r1 = e - which * 640;
      int ci = r1 / 80, r2 = r1 - ci * 80;
      int tr = r2 >> 3, c = r2 & 7;
      int ih = oh0 - 1 + tr;
      int cin = cc * 8 + ci;
      const float* src = which ? sc : sa;
      float v = 0.f;
      if (ih >= 0 && ih < H2) v = src[((size_t)b * 32 + cin) * NN + ih * 8 + c];
      tin[which * 960 + (ci * 10 + tr) * 12 + c] = v;
    }
    for (int e = tid; e < 4608; e += 128) {
      int voc_l = e & 63, t = e >> 6;
      const float* base = (voc_l < 32) ? (w51 + voc_l * 288) : (w52 + (voc_l - 32) * 288);
      twt[t * 64 + voc_l] = base[cc * 8 * 9 + t];
    }
    __syncthreads();
    const float* tbase = tin + (vocg < 8 ? 0 : 960);
#pragma unroll 1
    for (int ci = 0; ci < 8; ++ci) {
#pragma unroll
      for (int kh = 0; kh < 3; ++kh) {
        const float* rp = tbase + (ci * 10 + oh_l + kh) * 12;
        float4 a0 = *(const float4*)rp;
        float4 a1 = *(const float4*)(rp + 4);
        float rr[10];
        rr[0] = 0.f; rr[9] = 0.f;
        rr[1] = a0.x; rr[2] = a0.y; rr[3] = a0.z; rr[4] = a0.w;
        rr[5] = a1.x; rr[6] = a1.y; rr[7] = a1.z; rr[8] = a1.w;
#pragma unroll
        for (int kw = 0; kw < 3; ++kw) {
          float4 wv = *(const float4*)&twt[(ci * 9 + kh * 3 + kw) * 64 + vocg * 4];
#pragma unroll
          for (int ow = 0; ow < 8; ++ow) {
            float r = rr[ow + kw];
            acc[0][ow] = fmaf(r, wv.x, acc[0][ow]);
            acc[1][ow] = fmaf(r, wv.y, acc[1][ow]);
            acc[2][ow] = fmaf(r, wv.z, acc[2][ow]);
            acc[3][ow] = fmaf(r, wv.w, acc[3][ow]);
          }
        }
      }
    }
  }
  {
    float inv[4], sh[4];
#pragma unroll
    for (int vv = 0; vv < 4; ++vv) {
      int voc = vocg * 4 + vv;
      bool A = voc < 32;
      int ci = voc & 31;
      float sN = A ? s51[ci] : s52[ci];
      float bN = A ? b51[ci] : b52[ci];
      float mN = A ? m51[ci] : m52[ci];
      float vN = A ? v51[ci] : v52[ci];
      inv[vv] = sN * rsqrtf(vN + 1e-5f);
      sh[vv] = bN - mN * inv[vv];
    }
#pragma unroll
    for (int ow = 0; ow < 8; ++ow) {
      int pos = oh_l * 8 + ow;
#pragma unroll
      for (int vv = 0; vv < 4; ++vv) {
        float y = acc[vv][ow] * inv[vv] + sh[vv];
        tmid[pos * 65 + vocg * 4 + vv] = frelu(y);
      }
    }
  }
  __syncthreads();
  {
    const int o = tid >> 6, pos = tid & 63;
    const int oh = oh0 + (pos >> 3), ow = pos & 7;
    float a = b8[o];
    const float* wrow = w8 + o * 32;
#pragma unroll
    for (int c = 0; c < 32; ++c)
      a = fmaf(tmid[pos * 65 + c] + tmid[pos * 65 + 32 + c], wrow[c], a);
    if (oh < H2) out[((size_t)b * 2 + o) * NN + oh * 8 + ow] = a;
  }
}

// =========================== launcher ===========================
extern "C" void kernel_launch(void* const* d_in, const int* in_sizes, int n_in,
                              void* d_out, int out_size, void* d_ws, size_t ws_size,
                              hipStream_t stream) {
  (void)in_sizes; (void)n_in; (void)out_size; (void)ws_size;
  const float* x      = (const float*)d_in[0];
  const float* w1     = (const float*)d_in[1];
  const float* b1     = (const float*)d_in[2];
  const float* w2     = (const float*)d_in[3];
  const float* b2     = (const float*)d_in[4];
  const float* w3     = (const float*)d_in[5];
  const float* b3     = (const float*)d_in[6];
  const float* c5a_w  = (const float*)d_in[7];
  const float* bn5a_s = (const float*)d_in[8];
  const float* bn5a_b = (const float*)d_in[9];
  const float* bn5a_m = (const float*)d_in[10];
  const float* bn5a_v = (const float*)d_in[11];
  const float* c5c_w  = (const float*)d_in[12];
  const float* bn5c_s = (const float*)d_in[13];
  const float* bn5c_b = (const float*)d_in[14];
  const float* bn5c_m = (const float*)d_in[15];
  const float* bn5c_v = (const float*)d_in[16];
  const float* c51_w  = (const float*)d_in[17];
  const float* bn51_s = (const float*)d_in[18];
  const float* bn51_b = (const float*)d_in[19];
  const float* bn51_m = (const float*)d_in[20];
  const float* bn51_v = (const float*)d_in[21];
  const float* c52_w  = (const float*)d_in[22];
  const float* bn52_s = (const float*)d_in[23];
  const float* bn52_b = (const float*)d_in[24];
  const float* bn52_m = (const float*)d_in[25];
  const float* bn52_v = (const float*)d_in[26];
  const float* pam_qw = (const float*)d_in[27];
  const float* pam_qb = (const float*)d_in[28];
  const float* pam_kw = (const float*)d_in[29];
  const float* pam_kb = (const float*)d_in[30];
  const float* pam_vw = (const float*)d_in[31];
  const float* pam_vb = (const float*)d_in[32];
  const float* pgamma = (const float*)d_in[33];
  const float* cgamma = (const float*)d_in[34];
  const float* c8_w   = (const float*)d_in[35];
  const float* c8_b   = (const float*)d_in[36];

  float* W    = (float*)d_ws;
  float* h1   = W + OFF_H1;
  float* p2   = W + OFF_P2;
  float* p3   = W + OFF_P3;
  float* f1   = W + OFF_F1;
  float* f2   = W + OFF_F2;
  float* qbuf = W + OFF_Q;
  float* kbuf = W + OFF_K;
  float* vbuf = W + OFF_V;
  float* sab  = W + OFF_SA;
  float* scb  = W + OFF_SC;
  float* accp = W + OFF_ACCP;
  float* mlb  = W + OFF_ML;
  float* enb  = W + OFF_EN;
  float* outp = (float*)d_out;

  k_conv1<<<dim3(65, 16, 4), 256, 0, stream>>>(x, w1, b1, h1);
  k_conv2<<<dim3(33, 4, 4), 128, 0, stream>>>(h1, w2, b2, p2);
  k_conv3<<<dim3(33, 4, 4), 128, 0, stream>>>(p2, w3, b3, p3);
  k_c5<<<dim3(65, 4), 128, 0, stream>>>(p3,
                                        c5a_w, bn5a_s, bn5a_b, bn5a_m, bn5a_v,
                                        c5c_w, bn5c_s, bn5c_b, bn5c_m, bn5c_v,
                                        f1, f2);
  k_qkv<<<dim3(17, 40, 4), 256, 0, stream>>>(f1, pam_qw, pam_qb, pam_kw, pam_kb,
                                             pam_vw, pam_vb, qbuf, kbuf, vbuf);
  k_zero<<<dim3(16), 256, 0, stream>>>(enb);
  k_flash<<<dim3(17, NSPLIT, 4), 256, 0, stream>>>(qbuf, kbuf, vbuf, accp, mlb);
  k_energy<<<dim3(17, 4), 256, 0, stream>>>(f2, enb);
  k_combine<<<dim3(17, 32, 4), 256, 0, stream>>>(accp, mlb, f1, pgamma, sab);
  k_cam<<<dim3(65, 4), 64, 0, stream>>>(f2, enb, cgamma, scb);
  k_final<<<dim3(65, 4), 128, 0, stream>>>(sab, scb,
                                           c51_w, bn51_s, bn51_b, bn51_m, bn51_v,
                                           c52_w, bn52_s, bn52_b, bn52_m, bn52_v,
                                           c8_w, c8_b, outp);
}

// Round 4
// 1549.013 us; speedup vs baseline: 2.2483x; 1.3445x over previous
//
#include <hip/hip_runtime.h>
#include <cstddef>

// ---------------- problem dims ----------------
constexpr int BB   = 4;
constexpr int LX   = 126975;
constexpr int H0   = 4096, W0 = 61;          // c_in spatial
constexpr int C1   = 128, H1 = 1025, W1 = 16;
constexpr int C2   = 256, H2 = 513,  W2 = 8;
constexpr int C3   = 128;
constexpr int NN   = H2 * W2;                // 4104
constexpr int NSPLIT = 15;                   // attention j-splits
constexpr int JSPAN  = 288;                  // 32-aligned; 15*288 >= 4104
constexpr int NPAD   = 4104;                 // partial-row stride (16B-aligned)

// ---------------- workspace layout (float offsets), lifetime-overlapped ----
constexpr size_t SZ_H1    = (size_t)BB * C1 * H1 * W1;        // 8,396,800
constexpr size_t SZ_P2    = (size_t)BB * C2 * NN;             // 4,202,496
constexpr size_t SZ_F     = (size_t)BB * 32 * NN;             //   525,312
constexpr size_t SZ_QK    = (size_t)BB * 4 * NN;              //    65,664
constexpr size_t SZ_ACCP  = (size_t)NSPLIT * BB * 32 * NPAD;  // 7,879,680
constexpr size_t SZ_ML    = (size_t)NSPLIT * BB * 2 * NPAD;   //   492,480

constexpr size_t OFF_H1   = 0;
constexpr size_t OFF_P3   = 0;                  // reuses h1 (dead after conv2)
constexpr size_t OFF_ACCP = 0;                  // reuses p3 (dead after c5)
constexpr size_t OFF_ML   = OFF_ACCP + SZ_ACCP; // ends 8,372,160 < 8,396,800
constexpr size_t RB       = SZ_H1;              // 8,396,800
constexpr size_t OFF_P2   = RB;
constexpr size_t OFF_F1   = RB;                 // reuses p2 (dead after conv3)
constexpr size_t OFF_F2   = OFF_F1 + SZ_F;
constexpr size_t OFF_Q    = OFF_F2 + SZ_F;
constexpr size_t OFF_K    = OFF_Q  + SZ_QK;
constexpr size_t OFF_V    = OFF_K  + SZ_QK;
constexpr size_t OFF_SA   = OFF_V  + SZ_F;
constexpr size_t OFF_SC   = OFF_SA + SZ_F;
constexpr size_t OFF_EN   = RB + SZ_P2;         // 4096 floats

__device__ __forceinline__ float frelu(float x) { return x > 0.f ? x : 0.f; }

// ================= conv1: 8x8 s4 p4, cin=1, 128 oc, +bias+relu ================
// grid (65, 16, 4), block 256.
__global__ __launch_bounds__(256) void k_conv1(const float* __restrict__ x,
                                               const float* __restrict__ w1,
                                               const float* __restrict__ b1,
                                               float* __restrict__ h1) {
  __shared__ __align__(16) float tile[68 * 68];
  const int oh0 = blockIdx.x * 16;
  const int oc0 = blockIdx.y * 8;
  const int b   = blockIdx.z;
  const int tid = threadIdx.x;
  const int ih0 = oh0 * 4 - 4;
  for (int e = tid; e < 68 * 68; e += 256) {
    int row = e / 68, col = e - row * 68;
    int ih = ih0 + row, iw = col - 4;
    float v = 0.f;
    if (ih >= 0 && ih < H0 && iw >= 0 && iw < W0) {
      int l   = ih * W0 + iw;
      int pos = (l >> 12) * 2048 + (l & 4095);
      if (pos < LX) v = x[(size_t)b * LX + pos];
    }
    tile[e] = v;
  }
  __syncthreads();
  const int oh_l = tid >> 4, ow = tid & 15;
  float acc[8];
#pragma unroll
  for (int o = 0; o < 8; ++o) acc[o] = 0.f;
#pragma unroll
  for (int kh = 0; kh < 8; ++kh) {
    const float* rp = &tile[(4 * oh_l + kh) * 68 + 4 * ow];
    float4 a0 = *(const float4*)rp;
    float4 a1 = *(const float4*)(rp + 4);
    float r[8] = {a0.x, a0.y, a0.z, a0.w, a1.x, a1.y, a1.z, a1.w};
#pragma unroll
    for (int kw = 0; kw < 8; ++kw) {
#pragma unroll
      for (int o = 0; o < 8; ++o)
        acc[o] = fmaf(r[kw], w1[(oc0 + o) * 64 + kh * 8 + kw], acc[o]);
    }
  }
  const int oh = oh0 + oh_l;
  if (oh < H1) {
#pragma unroll
    for (int o = 0; o < 8; ++o) {
      float v = frelu(acc[o] + b1[oc0 + o]);
      h1[(((size_t)b * C1 + oc0 + o) * H1 + oh) * W1 + ow] = v;
    }
  }
}

// ================= conv2: 5x5 s2 p2, full cin 128, +bias+relu ================
// grid (65, 4, 4), block 256 (4 waves): tile oh8 x oc64; thread = 2oc x 8ow.
// 1040 blocks -> ~4 blocks/CU = 16 waves/CU.  Weight LDS stride 66 (conflict-
// free b64 reads, 2-way max on writes); t-major weight staging (coalesced).
__global__ __launch_bounds__(256) void k_conv2(const float* __restrict__ h1,
                                               const float* __restrict__ w2,
                                               const float* __restrict__ b2,
                                               float* __restrict__ p2) {
  __shared__ __align__(16) float tin[4 * 19 * 20];   // 1520
  __shared__ __align__(16) float twt[100 * 66];      // 6600
  const int oh0 = blockIdx.x * 8;
  const int oc0 = blockIdx.y * 64;
  const int b   = blockIdx.z;
  const int tid = threadIdx.x;
  const int oh_l = tid & 7, ocg = tid >> 3;          // ocg 0..31 -> 2 oc
  float acc[2][8] = {};
  for (int cc = 0; cc < 32; ++cc) {
    __syncthreads();
    for (int e = tid; e < 4 * 19 * 16; e += 256) {
      int ci = e / 304, r = e - ci * 304;
      int tr = r >> 4, c = r & 15;
      int ih = oh0 * 2 - 2 + tr;
      int cin = cc * 4 + ci;
      float v = 0.f;
      if (ih >= 0 && ih < H1) v = h1[(((size_t)b * C1 + cin) * H1 + ih) * W1 + c];
      tin[(ci * 19 + tr) * 20 + c] = v;
    }
    for (int e = tid; e < 6400; e += 256) {
      int oc_l = e / 100, t = e - oc_l * 100;
      twt[t * 66 + oc_l] = w2[(size_t)(oc0 + oc_l) * 3200 + cc * 100 + t];
    }
    __syncthreads();
#pragma unroll 1
    for (int ci = 0; ci < 4; ++ci) {
#pragma unroll
      for (int kh = 0; kh < 5; ++kh) {
        const float* rp = &tin[(ci * 19 + 2 * oh_l + kh) * 20];
        float4 a0 = *(const float4*)rp;
        float4 a1 = *(const float4*)(rp + 4);
        float4 a2 = *(const float4*)(rp + 8);
        float4 a3 = *(const float4*)(rp + 12);
        float rr[19];
        rr[0] = 0.f; rr[1] = 0.f; rr[18] = 0.f;
        rr[2] = a0.x; rr[3] = a0.y; rr[4] = a0.z; rr[5] = a0.w;
        rr[6] = a1.x; rr[7] = a1.y; rr[8] = a1.z; rr[9] = a1.w;
        rr[10] = a2.x; rr[11] = a2.y; rr[12] = a2.z; rr[13] = a2.w;
        rr[14] = a3.x; rr[15] = a3.y; rr[16] = a3.z; rr[17] = a3.w;
#pragma unroll
        for (int kw = 0; kw < 5; ++kw) {
          float2 wv = *(const float2*)&twt[(ci * 25 + kh * 5 + kw) * 66 + ocg * 2];
#pragma unroll
          for (int ow = 0; ow < 8; ++ow) {
            float r = rr[2 * ow + kw];
            acc[0][ow] = fmaf(r, wv.x, acc[0][ow]);
            acc[1][ow] = fmaf(r, wv.y, acc[1][ow]);
          }
        }
      }
    }
  }
  const int oh = oh0 + oh_l;
  if (oh < H2) {
#pragma unroll
    for (int o = 0; o < 2; ++o) {
      int oc = oc0 + ocg * 2 + o;
      float bo = b2[oc];
      float* dst = &p2[((size_t)b * C2 + oc) * NN + oh * 8];
      *(float4*)dst       = make_float4(frelu(acc[o][0] + bo), frelu(acc[o][1] + bo),
                                        frelu(acc[o][2] + bo), frelu(acc[o][3] + bo));
      *(float4*)(dst + 4) = make_float4(frelu(acc[o][4] + bo), frelu(acc[o][5] + bo),
                                        frelu(acc[o][6] + bo), frelu(acc[o][7] + bo));
    }
  }
}

// ================= conv3: 3x3 s1 p1, full cin 256, +bias+relu ================
// grid (65, 2, 4), block 256: tile oh8 x oc64; thread = 2oc x 8ow.  CC=8.
__global__ __launch_bounds__(256) void k_conv3(const float* __restrict__ p2,
                                               const float* __restrict__ w3,
                                               const float* __restrict__ b3,
                                               float* __restrict__ p3) {
  __shared__ __align__(16) float tin[8 * 10 * 12];   // 960
  __shared__ __align__(16) float twt[72 * 66];       // 4752
  const int oh0 = blockIdx.x * 8;
  const int oc0 = blockIdx.y * 64;
  const int b   = blockIdx.z;
  const int tid = threadIdx.x;
  const int oh_l = tid & 7, ocg = tid >> 3;
  float acc[2][8] = {};
  for (int cc = 0; cc < 32; ++cc) {
    __syncthreads();
    for (int e = tid; e < 640; e += 256) {
      int ci = e / 80, r = e - ci * 80;
      int tr = r >> 3, c = r & 7;
      int ih = oh0 - 1 + tr;
      int cin = cc * 8 + ci;
      float v = 0.f;
      if (ih >= 0 && ih < H2) v = p2[((size_t)b * C2 + cin) * NN + ih * 8 + c];
      tin[(ci * 10 + tr) * 12 + c] = v;
    }
    for (int e = tid; e < 4608; e += 256) {
      int oc_l = e / 72, t = e - oc_l * 72;
      twt[t * 66 + oc_l] = w3[(size_t)(oc0 + oc_l) * 2304 + cc * 72 + t];
    }
    __syncthreads();
#pragma unroll 1
    for (int ci = 0; ci < 8; ++ci) {
#pragma unroll
      for (int kh = 0; kh < 3; ++kh) {
        const float* rp = &tin[(ci * 10 + oh_l + kh) * 12];
        float4 a0 = *(const float4*)rp;
        float4 a1 = *(const float4*)(rp + 4);
        float rr[10];
        rr[0] = 0.f; rr[9] = 0.f;
        rr[1] = a0.x; rr[2] = a0.y; rr[3] = a0.z; rr[4] = a0.w;
        rr[5] = a1.x; rr[6] = a1.y; rr[7] = a1.z; rr[8] = a1.w;
#pragma unroll
        for (int kw = 0; kw < 3; ++kw) {
          float2 wv = *(const float2*)&twt[(ci * 9 + kh * 3 + kw) * 66 + ocg * 2];
#pragma unroll
          for (int ow = 0; ow < 8; ++ow) {
            float r = rr[ow + kw];
            acc[0][ow] = fmaf(r, wv.x, acc[0][ow]);
            acc[1][ow] = fmaf(r, wv.y, acc[1][ow]);
          }
        }
      }
    }
  }
  const int oh = oh0 + oh_l;
  if (oh < H2) {
#pragma unroll
    for (int o = 0; o < 2; ++o) {
      int oc = oc0 + ocg * 2 + o;
      float bo = b3[oc];
      float* dst = &p3[((size_t)b * C3 + oc) * NN + oh * 8];
      *(float4*)dst       = make_float4(frelu(acc[o][0] + bo), frelu(acc[o][1] + bo),
                                        frelu(acc[o][2] + bo), frelu(acc[o][3] + bo));
      *(float4*)(dst + 4) = make_float4(frelu(acc[o][4] + bo), frelu(acc[o][5] + bo),
                                        frelu(acc[o][6] + bo), frelu(acc[o][7] + bo));
    }
  }
}

// ========== fused conv5a + conv5c (3x3, cin128 -> 32+32) + BN + ReLU ==========
// grid (65, 4), block 128. voc 0..31 -> feat1 (c5a), 32..63 -> feat2 (c5c).
__global__ __launch_bounds__(128) void k_c5(const float* __restrict__ p3,
                                            const float* __restrict__ wa,
                                            const float* __restrict__ sa5, const float* __restrict__ ba5,
                                            const float* __restrict__ ma5, const float* __restrict__ va5,
                                            const float* __restrict__ wc,
                                            const float* __restrict__ sc5, const float* __restrict__ bc5,
                                            const float* __restrict__ mc5, const float* __restrict__ vc5,
                                            float* __restrict__ f1, float* __restrict__ f2) {
  __shared__ __align__(16) float tin[8 * 10 * 12];  // 960
  __shared__ __align__(16) float twt[72 * 64];
  const int oh0 = blockIdx.x * 8;
  const int b   = blockIdx.y;
  const int tid = threadIdx.x;
  const int vocg = tid >> 3, oh_l = tid & 7;
  float acc[4][8] = {};
  for (int cc = 0; cc < 16; ++cc) {
    __syncthreads();
    for (int e = tid; e < 640; e += 128) {
      int ci = e / 80, r = e - ci * 80;
      int tr = r >> 3, c = r & 7;
      int ih = oh0 - 1 + tr;
      int cin = cc * 8 + ci;
      float v = 0.f;
      if (ih >= 0 && ih < H2) v = p3[((size_t)b * C3 + cin) * NN + ih * 8 + c];
      tin[(ci * 10 + tr) * 12 + c] = v;
    }
    for (int e = tid; e < 4608; e += 128) {
      int voc_l = e & 63, t = e >> 6;
      const float* base = (voc_l < 32) ? (wa + (size_t)voc_l * 1152) : (wc + (size_t)(voc_l - 32) * 1152);
      twt[t * 64 + voc_l] = base[cc * 8 * 9 + t];
    }
    __syncthreads();
#pragma unroll 1
    for (int ci = 0; ci < 8; ++ci) {
#pragma unroll
      for (int kh = 0; kh < 3; ++kh) {
        const float* rp = &tin[(ci * 10 + oh_l + kh) * 12];
        float4 a0 = *(const float4*)rp;
        float4 a1 = *(const float4*)(rp + 4);
        float rr[10];
        rr[0] = 0.f; rr[9] = 0.f;
        rr[1] = a0.x; rr[2] = a0.y; rr[3] = a0.z; rr[4] = a0.w;
        rr[5] = a1.x; rr[6] = a1.y; rr[7] = a1.z; rr[8] = a1.w;
#pragma unroll
        for (int kw = 0; kw < 3; ++kw) {
          float4 wv = *(const float4*)&twt[(ci * 9 + kh * 3 + kw) * 64 + vocg * 4];
#pragma unroll
          for (int ow = 0; ow < 8; ++ow) {
            float r = rr[ow + kw];
            acc[0][ow] = fmaf(r, wv.x, acc[0][ow]);
            acc[1][ow] = fmaf(r, wv.y, acc[1][ow]);
            acc[2][ow] = fmaf(r, wv.z, acc[2][ow]);
            acc[3][ow] = fmaf(r, wv.w, acc[3][ow]);
          }
        }
      }
    }
  }
  const int oh = oh0 + oh_l;
  if (oh < H2) {
#pragma unroll
    for (int vv = 0; vv < 4; ++vv) {
      int voc = vocg * 4 + vv;
      bool A = voc < 32;
      int ci = voc & 31;
      float sN = A ? sa5[ci] : sc5[ci];
      float bN = A ? ba5[ci] : bc5[ci];
      float mN = A ? ma5[ci] : mc5[ci];
      float vN = A ? va5[ci] : vc5[ci];
      float inv = sN * rsqrtf(vN + 1e-5f);
      float sh  = bN - mN * inv;
      float* dst = (A ? f1 : f2) + ((size_t)b * 32 + ci) * NN + oh * 8;
      float y[8];
#pragma unroll
      for (int ow = 0; ow < 8; ++ow) y[ow] = frelu(acc[vv][ow] * inv + sh);
      *(float4*)dst       = make_float4(y[0], y[1], y[2], y[3]);
      *(float4*)(dst + 4) = make_float4(y[4], y[5], y[6], y[7]);
    }
  }
}

// ================= 1x1 convs for q, k, v =================
// grid (17, 40, 4), block 256.  y: 0-3 q, 4-7 k, 8-39 v.
__global__ __launch_bounds__(256) void k_qkv(const float* __restrict__ f1,
                                             const float* __restrict__ qw, const float* __restrict__ qbv,
                                             const float* __restrict__ kwp, const float* __restrict__ kbv,
                                             const float* __restrict__ vwp, const float* __restrict__ vbv,
                                             float* __restrict__ qo, float* __restrict__ ko,
                                             float* __restrict__ vo) {
  const int n = blockIdx.x * 256 + threadIdx.x;
  if (n >= NN) return;
  const int ocv = blockIdx.y, b = blockIdx.z;
  const float* w;
  float bias;
  float* dst;
  if (ocv < 4)      { w = qw + ocv * 32;        bias = qbv[ocv];     dst = qo + ((size_t)b * 4 + ocv) * NN; }
  else if (ocv < 8) { int o = ocv - 4; w = kwp + o * 32; bias = kbv[o]; dst = ko + ((size_t)b * 4 + o) * NN; }
  else              { int o = ocv - 8; w = vwp + o * 32; bias = vbv[o]; dst = vo + ((size_t)b * 32 + o) * NN; }
  float a = bias;
#pragma unroll
  for (int c = 0; c < 32; ++c) a = fmaf(f1[((size_t)b * 32 + c) * NN + n], w[c], a);
  dst[n] = a;
}

// ================= flash PAM attention, partial (j-split x15) =================
__device__ __forceinline__ float rmax32(const float (&p)[32]) {
  float x0 = p[0], x1 = p[1], x2 = p[2], x3 = p[3];
#pragma unroll
  for (int j = 4; j < 32; j += 4) {
    x0 = fmaxf(x0, p[j]); x1 = fmaxf(x1, p[j + 1]);
    x2 = fmaxf(x2, p[j + 2]); x3 = fmaxf(x3, p[j + 3]);
  }
  return fmaxf(fmaxf(x0, x1), fmaxf(x2, x3));
}
__device__ __forceinline__ float rsum32(const float (&p)[32]) {
  float x0 = p[0], x1 = p[1], x2 = p[2], x3 = p[3];
#pragma unroll
  for (int j = 4; j < 32; j += 4) { x0 += p[j]; x1 += p[j + 1]; x2 += p[j + 2]; x3 += p[j + 3]; }
  return (x0 + x1) + (x2 + x3);
}

// grid (17, 15, 4), block 256 (4 waves).
__global__ __launch_bounds__(256) void k_flash(const float* __restrict__ qb,
                                               const float* __restrict__ kb,
                                               const float* __restrict__ vb,
                                               float* __restrict__ accp,
                                               float* __restrict__ mlb) {
  __shared__ __align__(16) float ks[4 * 32];
  __shared__ __align__(16) float vs[32 * 32];
  const int tid = threadIdx.x;
  const int ia  = blockIdx.x * 256 + tid;
  const int sp  = blockIdx.y;
  const int b   = blockIdx.z;
  float q[4];
#pragma unroll
  for (int d = 0; d < 4; ++d)
    q[d] = (ia < NN) ? qb[((size_t)b * 4 + d) * NN + ia] : 0.f;
  float m = -1e30f, l = 0.f;
  float acc[32];
#pragma unroll
  for (int c = 0; c < 32; ++c) acc[c] = 0.f;
  const int jbeg = sp * JSPAN;
  const int jend = (jbeg + JSPAN < NN) ? jbeg + JSPAN : NN;
  const int cs = tid >> 3, j4 = (tid & 7) * 4;   // staging coords
  for (int j0 = jbeg; j0 < jend; j0 += 32) {
    const int nv = (jend - j0 < 32) ? jend - j0 : 32;
    __syncthreads();
    {
      const float* vsrc = &vb[((size_t)b * 32 + cs) * NN + j0 + j4];
      float4 v4;
      if (j4 + 4 <= nv) {
        v4 = *(const float4*)vsrc;
      } else {
        v4.x = (j4 + 0 < nv) ? vsrc[0] : 0.f;
        v4.y = (j4 + 1 < nv) ? vsrc[1] : 0.f;
        v4.z = (j4 + 2 < nv) ? vsrc[2] : 0.f;
        v4.w = (j4 + 3 < nv) ? vsrc[3] : 0.f;
      }
      *(float4*)&vs[cs * 32 + j4] = v4;
      if (tid < 32) {
        const int d = tid >> 3;
        const float* ksrc = &kb[((size_t)b * 4 + d) * NN + j0 + j4];
        float4 k4;
        if (j4 + 4 <= nv) {
          k4 = *(const float4*)ksrc;
        } else {
          k4.x = (j4 + 0 < nv) ? ksrc[0] : 0.f;
          k4.y = (j4 + 1 < nv) ? ksrc[1] : 0.f;
          k4.z = (j4 + 2 < nv) ? ksrc[2] : 0.f;
          k4.w = (j4 + 3 < nv) ? ksrc[3] : 0.f;
        }
        *(float4*)&ks[d * 32 + j4] = k4;
      }
    }
    __syncthreads();
    float p[32];
#pragma unroll
    for (int jj = 0; jj < 8; ++jj) {
      float4 k0 = *(const float4*)&ks[0 * 32 + 4 * jj];
      float4 k1 = *(const float4*)&ks[1 * 32 + 4 * jj];
      float4 k2 = *(const float4*)&ks[2 * 32 + 4 * jj];
      float4 k3 = *(const float4*)&ks[3 * 32 + 4 * jj];
      p[4 * jj + 0] = fmaf(q[0], k0.x, fmaf(q[1], k1.x, fmaf(q[2], k2.x, q[3] * k3.x)));
      p[4 * jj + 1] = fmaf(q[0], k0.y, fmaf(q[1], k1.y, fmaf(q[2], k2.y, q[3] * k3.y)));
      p[4 * jj + 2] = fmaf(q[0], k0.z, fmaf(q[1], k1.z, fmaf(q[2], k2.z, q[3] * k3.z)));
      p[4 * jj + 3] = fmaf(q[0], k0.w, fmaf(q[1], k1.w, fmaf(q[2], k2.w, q[3] * k3.w)));
    }
    if (nv < 32) {
#pragma unroll
      for (int j = 0; j < 32; ++j)
        if (j >= nv) p[j] = -1e30f;
    }
    float mn = fmaxf(m, rmax32(p));
    float f = __expf(m - mn);
    m = mn;
#pragma unroll
    for (int j = 0; j < 32; ++j) p[j] = __expf(p[j] - mn);
    l = fmaf(l, f, rsum32(p));
#pragma unroll
    for (int c = 0; c < 32; ++c) acc[c] *= f;
#pragma unroll
    for (int jj = 0; jj < 8; ++jj) {
      float4 p4 = make_float4(p[4 * jj], p[4 * jj + 1], p[4 * jj + 2], p[4 * jj + 3]);
#pragma unroll
      for (int c = 0; c < 32; ++c) {
        float4 vv = *(const float4*)&vs[c * 32 + 4 * jj];
        acc[c] = fmaf(p4.x, vv.x, fmaf(p4.y, vv.y, fmaf(p4.z, vv.z, fmaf(p4.w, vv.w, acc[c]))));
      }
    }
  }
  if (ia < NN) {
    const size_t sb4 = (size_t)(sp * 4 + b);
#pragma unroll
    for (int c = 0; c < 32; ++c)
      accp[(sb4 * 32 + c) * NPAD + ia] = acc[c];
    mlb[(sb4 * 2 + 0) * NPAD + ia] = m;
    mlb[(sb4 * 2 + 1) * NPAD + ia] = l;
  }
}

// ================= combine flash partials -> sa = gamma*attn@v + feat1 ============
// grid (17, 32, 4), block 256.
__global__ __launch_bounds__(256) void k_combine(const float* __restrict__ accp,
                                                 const float* __restrict__ mlb,
                                                 const float* __restrict__ f1,
                                                 const float* __restrict__ gamma,
                                                 float* __restrict__ sa) {
  const int n = blockIdx.x * 256 + threadIdx.x;
  if (n >= NN) return;
  const int c = blockIdx.y, b = blockIdx.z;
  float m[NSPLIT], l[NSPLIT];
#pragma unroll
  for (int s = 0; s < NSPLIT; ++s) {
    m[s] = mlb[((size_t)(s * 4 + b) * 2 + 0) * NPAD + n];
    l[s] = mlb[((size_t)(s * 4 + b) * 2 + 1) * NPAD + n];
  }
  float ms = m[0];
#pragma unroll
  for (int s = 1; s < NSPLIT; ++s) ms = fmaxf(ms, m[s]);
  float den = 0.f, num = 0.f;
#pragma unroll
  for (int s = 0; s < NSPLIT; ++s) {
    float w = __expf(m[s] - ms);
    den = fmaf(l[s], w, den);
    num = fmaf(w, accp[((size_t)(s * 4 + b) * 32 + c) * NPAD + n], num);
  }
  size_t o = ((size_t)b * 32 + c) * NN + n;
  sa[o] = gamma[0] * num / den + f1[o];
}

// ================= CAM: energy (atomic partials) ==============================
__global__ __launch_bounds__(256) void k_zero(float* __restrict__ p) {
  int i = blockIdx.x * 256 + threadIdx.x;
  if (i < 4096) p[i] = 0.f;
}

// grid (17, 4), block 256.
__global__ __launch_bounds__(256) void k_energy(const float* __restrict__ f2,
                                                float* __restrict__ energy) {
  __shared__ float fs[32 * 257];
  const int n0 = blockIdx.x * 256, b = blockIdx.y, tid = threadIdx.x;
  for (int e = tid; e < 32 * 256; e += 256) {
    int c = e >> 8, nl = e & 255;
    int n = n0 + nl;
    fs[c * 257 + nl] = (n < NN) ? f2[((size_t)b * 32 + c) * NN + n] : 0.f;
  }
  __syncthreads();
  const int cg = tid >> 4, dg = tid & 15;
  const int c0 = cg * 2, d0 = dg * 2;
  float e00 = 0.f, e01 = 0.f, e10 = 0.f, e11 = 0.f;
  for (int t = 0; t < 256; ++t) {
    float a0 = fs[c0 * 257 + t], a1 = fs[(c0 + 1) * 257 + t];
    float b0 = fs[d0 * 257 + t], b1 = fs[(d0 + 1) * 257 + t];
    e00 = fmaf(a0, b0, e00); e01 = fmaf(a0, b1, e01);
    e10 = fmaf(a1, b0, e10); e11 = fmaf(a1, b1, e11);
  }
  float* eb = energy + b * 1024;
  atomicAdd(&eb[c0 * 32 + d0], e00);
  atomicAdd(&eb[c0 * 32 + d0 + 1], e01);
  atomicAdd(&eb[(c0 + 1) * 32 + d0], e10);
  atomicAdd(&eb[(c0 + 1) * 32 + d0 + 1], e11);
}

// ======== CAM apply: cattn = softmax(maxE - E) rows; sc = g*cattn@f2 + f2 ========
// grid (65, 4), block 64.
__global__ __launch_bounds__(64) void k_cam(const float* __restrict__ f2,
                                            const float* __restrict__ energy,
                                            const float* __restrict__ gamma,
                                            float* __restrict__ sc) {
  __shared__ __align__(16) float cat[32 * 32];
  const int lane = threadIdx.x, b = blockIdx.y;
  const int n = blockIdx.x * 64 + lane;
  if (lane < 32) {
    const float* eb = energy + b * 1024 + lane * 32;
    float e[32];
#pragma unroll
    for (int d = 0; d < 32; ++d) e[d] = eb[d];
    float mn = e[0];
#pragma unroll
    for (int d = 1; d < 32; ++d) mn = fminf(mn, e[d]);
    float w[32];
    float sum = 0.f;
#pragma unroll
    for (int d = 0; d < 32; ++d) { w[d] = __expf(mn - e[d]); sum += w[d]; }
    float inv = 1.f / sum;
#pragma unroll
    for (int d = 0; d < 32; ++d) cat[lane * 32 + d] = w[d] * inv;
  }
  __syncthreads();
  const bool ok = n < NN;
  float f[32];
#pragma unroll
  for (int c = 0; c < 32; ++c) f[c] = ok ? f2[((size_t)b * 32 + c) * NN + n] : 0.f;
  const float g = gamma[0];
#pragma unroll
  for (int c = 0; c < 32; ++c) {
    float a = 0.f;
#pragma unroll
    for (int k4 = 0; k4 < 8; ++k4) {
      float4 cw = *(const float4*)&cat[c * 32 + 4 * k4];
      a = fmaf(cw.x, f[4 * k4], fmaf(cw.y, f[4 * k4 + 1], fmaf(cw.z, f[4 * k4 + 2], fmaf(cw.w, f[4 * k4 + 3], a))));
    }
    if (ok) sc[((size_t)b * 32 + c) * NN + n] = g * a + f[c];
  }
}

// ======== fused c51(sa)+BN+ReLU, c52(sc)+BN+ReLU, sum, conv8 1x1 -> out ========
// grid (65, 4), block 128.
__global__ __launch_bounds__(128) void k_final(const float* __restrict__ sa,
                                               const float* __restrict__ sc,
                                               const float* __restrict__ w51,
                                               const float* __restrict__ s51, const float* __restrict__ b51,
                                               const float* __restrict__ m51, const float* __restrict__ v51,
                                               const float* __restrict__ w52,
                                               const float* __restrict__ s52, const float* __restrict__ b52,
                                               const float* __restrict__ m52, const float* __restrict__ v52,
                                               const float* __restrict__ w8, const float* __restrict__ b8,
                                               float* __restrict__ out) {
  __shared__ __align__(16) float tin[2 * 8 * 10 * 12];  // 1920
  __shared__ __align__(16) float twt[72 * 64];          // 4608
  __shared__ float tmid[64 * 65];
  const int oh0 = blockIdx.x * 8;
  const int b   = blockIdx.y;
  const int tid = threadIdx.x;
  const int vocg = tid >> 3, oh_l = tid & 7;
  float acc[4][8] = {};
  for (int cc = 0; cc < 4; ++cc) {
    __syncthreads();
    for (int e = tid; e < 1280; e += 128) {
      int which = (e >= 640) ? 1 : 0;
      int r1 = e - which * 640;
      int ci = r1 / 80, r2 = r1 - ci * 80;
      int tr = r2 >> 3, c = r2 & 7;
      int ih = oh0 - 1 + tr;
      int cin = cc * 8 + ci;
      const float* src = which ? sc : sa;
      float v = 0.f;
      if (ih >= 0 && ih < H2) v = src[((size_t)b * 32 + cin) * NN + ih * 8 + c];
      tin[which * 960 + (ci * 10 + tr) * 12 + c] = v;
    }
    for (int e = tid; e < 4608; e += 128) {
      int voc_l = e & 63, t = e >> 6;
      const float* base = (voc_l < 32) ? (w51 + voc_l * 288) : (w52 + (voc_l - 32) * 288);
      twt[t * 64 + voc_l] = base[cc * 8 * 9 + t];
    }
    __syncthreads();
    const float* tbase = tin + (vocg < 8 ? 0 : 960);
#pragma unroll 1
    for (int ci = 0; ci < 8; ++ci) {
#pragma unroll
      for (int kh = 0; kh < 3; ++kh) {
        const float* rp = tbase + (ci * 10 + oh_l + kh) * 12;
        float4 a0 = *(const float4*)rp;
        float4 a1 = *(const float4*)(rp + 4);
        float rr[10];
        rr[0] = 0.f; rr[9] = 0.f;
        rr[1] = a0.x; rr[2] = a0.y; rr[3] = a0.z; rr[4] = a0.w;
        rr[5] = a1.x; rr[6] = a1.y; rr[7] = a1.z; rr[8] = a1.w;
#pragma unroll
        for (int kw = 0; kw < 3; ++kw) {
          float4 wv = *(const float4*)&twt[(ci * 9 + kh * 3 + kw) * 64 + vocg * 4];
#pragma unroll
          for (int ow = 0; ow < 8; ++ow) {
            float r = rr[ow + kw];
            acc[0][ow] = fmaf(r, wv.x, acc[0][ow]);
            acc[1][ow] = fmaf(r, wv.y, acc[1][ow]);
            acc[2][ow] = fmaf(r, wv.z, acc[2][ow]);
            acc[3][ow] = fmaf(r, wv.w, acc[3][ow]);
          }
        }
      }
    }
  }
  {
    float inv[4], sh[4];
#pragma unroll
    for (int vv = 0; vv < 4; ++vv) {
      int voc = vocg * 4 + vv;
      bool A = voc < 32;
      int ci = voc & 31;
      float sN = A ? s51[ci] : s52[ci];
      float bN = A ? b51[ci] : b52[ci];
      float mN = A ? m51[ci] : m52[ci];
      float vN = A ? v51[ci] : v52[ci];
      inv[vv] = sN * rsqrtf(vN + 1e-5f);
      sh[vv] = bN - mN * inv[vv];
    }
#pragma unroll
    for (int ow = 0; ow < 8; ++ow) {
      int pos = oh_l * 8 + ow;
#pragma unroll
      for (int vv = 0; vv < 4; ++vv) {
        float y = acc[vv][ow] * inv[vv] + sh[vv];
        tmid[pos * 65 + vocg * 4 + vv] = frelu(y);
      }
    }
  }
  __syncthreads();
  {
    const int o = tid >> 6, pos = tid & 63;
    const int oh = oh0 + (pos >> 3), ow = pos & 7;
    float a = b8[o];
    const float* wrow = w8 + o * 32;
#pragma unroll
    for (int c = 0; c < 32; ++c)
      a = fmaf(tmid[pos * 65 + c] + tmid[pos * 65 + 32 + c], wrow[c], a);
    if (oh < H2) out[((size_t)b * 2 + o) * NN + oh * 8 + ow] = a;
  }
}

// =========================== launcher ===========================
extern "C" void kernel_launch(void* const* d_in, const int* in_sizes, int n_in,
                              void* d_out, int out_size, void* d_ws, size_t ws_size,
                              hipStream_t stream) {
  (void)in_sizes; (void)n_in; (void)out_size; (void)ws_size;
  const float* x      = (const float*)d_in[0];
  const float* w1     = (const float*)d_in[1];
  const float* b1     = (const float*)d_in[2];
  const float* w2     = (const float*)d_in[3];
  const float* b2     = (const float*)d_in[4];
  const float* w3     = (const float*)d_in[5];
  const float* b3     = (const float*)d_in[6];
  const float* c5a_w  = (const float*)d_in[7];
  const float* bn5a_s = (const float*)d_in[8];
  const float* bn5a_b = (const float*)d_in[9];
  const float* bn5a_m = (const float*)d_in[10];
  const float* bn5a_v = (const float*)d_in[11];
  const float* c5c_w  = (const float*)d_in[12];
  const float* bn5c_s = (const float*)d_in[13];
  const float* bn5c_b = (const float*)d_in[14];
  const float* bn5c_m = (const float*)d_in[15];
  const float* bn5c_v = (const float*)d_in[16];
  const float* c51_w  = (const float*)d_in[17];
  const float* bn51_s = (const float*)d_in[18];
  const float* bn51_b = (const float*)d_in[19];
  const float* bn51_m = (const float*)d_in[20];
  const float* bn51_v = (const float*)d_in[21];
  const float* c52_w  = (const float*)d_in[22];
  const float* bn52_s = (const float*)d_in[23];
  const float* bn52_b = (const float*)d_in[24];
  const float* bn52_m = (const float*)d_in[25];
  const float* bn52_v = (const float*)d_in[26];
  const float* pam_qw = (const float*)d_in[27];
  const float* pam_qb = (const float*)d_in[28];
  const float* pam_kw = (const float*)d_in[29];
  const float* pam_kb = (const float*)d_in[30];
  const float* pam_vw = (const float*)d_in[31];
  const float* pam_vb = (const float*)d_in[32];
  const float* pgamma = (const float*)d_in[33];
  const float* cgamma = (const float*)d_in[34];
  const float* c8_w   = (const float*)d_in[35];
  const float* c8_b   = (const float*)d_in[36];

  float* W    = (float*)d_ws;
  float* h1   = W + OFF_H1;
  float* p2   = W + OFF_P2;
  float* p3   = W + OFF_P3;
  float* f1   = W + OFF_F1;
  float* f2   = W + OFF_F2;
  float* qbuf = W + OFF_Q;
  float* kbuf = W + OFF_K;
  float* vbuf = W + OFF_V;
  float* sab  = W + OFF_SA;
  float* scb  = W + OFF_SC;
  float* accp = W + OFF_ACCP;
  float* mlb  = W + OFF_ML;
  float* enb  = W + OFF_EN;
  float* outp = (float*)d_out;

  k_conv1<<<dim3(65, 16, 4), 256, 0, stream>>>(x, w1, b1, h1);
  k_conv2<<<dim3(65, 4, 4), 256, 0, stream>>>(h1, w2, b2, p2);
  k_conv3<<<dim3(65, 2, 4), 256, 0, stream>>>(p2, w3, b3, p3);
  k_c5<<<dim3(65, 4), 128, 0, stream>>>(p3,
                                        c5a_w, bn5a_s, bn5a_b, bn5a_m, bn5a_v,
                                        c5c_w, bn5c_s, bn5c_b, bn5c_m, bn5c_v,
                                        f1, f2);
  k_qkv<<<dim3(17, 40, 4), 256, 0, stream>>>(f1, pam_qw, pam_qb, pam_kw, pam_kb,
                                             pam_vw, pam_vb, qbuf, kbuf, vbuf);
  k_zero<<<dim3(16), 256, 0, stream>>>(enb);
  k_flash<<<dim3(17, NSPLIT, 4), 256, 0, stream>>>(qbuf, kbuf, vbuf, accp, mlb);
  k_energy<<<dim3(17, 4), 256, 0, stream>>>(f2, enb);
  k_combine<<<dim3(17, 32, 4), 256, 0, stream>>>(accp, mlb, f1, pgamma, sab);
  k_cam<<<dim3(65, 4), 64, 0, stream>>>(f2, enb, cgamma, scb);
  k_final<<<dim3(65, 4), 128, 0, stream>>>(sab, scb,
                                           c51_w, bn51_s, bn51_b, bn51_m, bn51_v,
                                           c52_w, bn52_s, bn52_b, bn52_m, bn52_v,
                                           c8_w, c8_b, outp);
}